// Round 3
// baseline (745.441 us; speedup 1.0000x reference)
//
#include <hip/hip_runtime.h>
#include <math.h>

// ---------------- problem constants ----------------
#define BB 8
#define LL 8192
#define DD 128
#define NCH 8
#define NST 64
#define TAPS 32          // e^{-0.5*32} ~ 1e-7 relative: FIR truncation far below threshold
#define NOUTD 375

// ---------------- MFMA types ----------------
typedef __attribute__((ext_vector_type(8))) short bf16x8;
typedef __attribute__((ext_vector_type(4))) float f32x4;
#define MFMA16(a,b,c) __builtin_amdgcn_mfma_f32_16x16x32_bf16((a),(b),(c),0,0,0)

struct __align__(8) us4 { unsigned short x,y,z,w; };

__device__ __forceinline__ unsigned short f2b(float f) {   // fp32 -> bf16 RNE
  unsigned x = __float_as_uint(f);
  unsigned r = (x + 0x7fffu + ((x >> 16) & 1u)) >> 16;
  return (unsigned short)r;
}
__device__ __forceinline__ float b2f(unsigned short u) {
  return __uint_as_float(((unsigned)u) << 16);
}
__device__ __forceinline__ float silu_f(float x){ return x / (1.f + expf(-x)); }

// ---------------- workspace layout (float offsets) ----------------
static constexpr size_t WS_H      = 0;                             // [B,L,128] fp32 residual (buffer 0)
static constexpr size_t WS_LOGITS = WS_H      + (size_t)BB*LL*DD;  // [B,L]
static constexpr size_t WS_SEGM   = WS_LOGITS + (size_t)BB*LL;     // [B,16]
static constexpr size_t WS_SEGS   = WS_SEGM   + BB*16;             // [B,16]
static constexpr size_t WS_SEGV   = WS_SEGS   + BB*16;             // [B,16,128]
static constexpr size_t WS_SCALE  = WS_SEGV   + (size_t)BB*16*DD;  // [7,B,128]
static constexpr size_t WS_SHIFT  = WS_SCALE  + (size_t)7*BB*DD;   // [7,B,128]
static constexpr size_t WS_C1     = WS_SHIFT  + (size_t)7*BB*DD;   // [3,128]
static constexpr size_t WS_C2     = WS_C1     + 3*DD;              // [3,128]
static constexpr size_t WS_KTAB   = WS_C2     + 3*DD;              // [3,8,32] (legacy, unused)
static constexpr size_t WS_GAW    = WS_KTAB   + 3*NCH*TAPS;        // [128]
static constexpr size_t WS_ASCAL  = WS_GAW    + DD;                // 2 (+pad)
static constexpr size_t WS_BASE   = WS_ASCAL  + 32;                // [B,128]
static constexpr size_t WS_BIAS1  = WS_BASE   + BB*DD;             // [B,448] folded gen bias
// ----- ushort (bf16) regions, float-offset based -----
static constexpr size_t WS_ZB_F   = WS_BIAS1  + (size_t)BB*448;    // [B,128ch,L] bf16 z (fallback only)
static constexpr size_t WS_WGT_F  = WS_ZB_F   + (size_t)BB*LL*DD/2; // [3,128n,128k] bf16 ln-folded inW^T
static constexpr size_t WS_WOT_F  = WS_WGT_F  + (size_t)3*DD*DD/2;  // [3,128n,128k] bf16 outW^T
static constexpr size_t WS_WO2T_F = WS_WOT_F  + (size_t)3*DD*DD/2;  // [7,192n,64k] bf16 genW_o^T
static constexpr size_t WS_WCT_F  = WS_WO2T_F + (size_t)7*192*64/2; // [B,448n,128k] bf16 folded gen W
static constexpr size_t WS_TM_F   = WS_WCT_F  + (size_t)BB*448*DD/2; // [3,8,64,128] bf16 Toeplitz conv
static constexpr size_t WS_TOTAL  = WS_TM_F   + (size_t)3*NCH*64*128/2;
static constexpr size_t WS_H1     = WS_TOTAL;                      // [B,L,128] fp32 residual (buffer 1, fused path)
static constexpr size_t WS_FUSED_END = WS_H1 + (size_t)BB*LL*DD;

__device__ __constant__ int c_offs_d[7] = {0, 1, 2, 102, 294, 358, 370};
__device__ __constant__ int c_dims_d[7] = {1, 1, 100, 192, 64, 12, 5};
// 27 n-tiles of GEMM2 (block-diagonal): (head, local col tile)
__device__ __constant__ int t_hd[27] = {0,1,2,2,2,2,2,2,2,3,3,3,3,3,3,3,3,3,3,3,3,4,4,4,4,5,6};
__device__ __constant__ int t_nl[27] = {0,0,0,1,2,3,4,5,6,0,1,2,3,4,5,6,7,8,9,10,11,0,1,2,3,0,0};

// ================= K0: fold weights, build Toeplitz conv mats, bf16 weight transposes =================
// grid 35: blk 0-2: per-layer wgt/wot/C1/C2; blk 3-26: Toeplitz (ly,cx); blk 27: BASE+GAW+ASCAL;
// blk 28-34: wo2t per head
__global__ __launch_bounds__(256) void k0_setup(
    const float* s4_ln_g, const float* s4_ln_b, const float* s4_inW, const float* s4_inb,
    const float* s4_outW,
    const float* lam_re, const float* lam_im, const float* Bn, const float* Cre, const float* Cim,
    const float* attn_g, const float* attn_lnb, const float* attn_w, const float* attn_bias,
    const int* singer_id, const int* language_id,
    const float* singer_emb, const float* lang_emb, const float* inW, const float* inb,
    const float* genW_o, const float* Dc, float* ws)
{
  int blk = blockIdx.x, tid = threadIdx.x;
  if (blk < 3) {
    // ---- per-layer: wgt (LN-folded inW^T), wot (outW^T), C1/C2 ----
    __shared__ __align__(16) unsigned short tile[128*136];  // 34.8KB
    __shared__ float c1p[256], c2p[256];
    int ly = blk;
    int n = tid & 127;
    float c1a = 0.f, c2a = 0.f;
    for (int j = 0; j < 64; ++j) {
      int k = (tid >> 7) + 2*j;
      float v  = s4_inW[((size_t)ly*DD + k)*DD + n];       // coalesced
      float gk = s4_ln_g[ly*DD + k];
      float bk = s4_ln_b[ly*DD + k];
      tile[k*136 + n] = f2b(gk*v);
      c1a += gk*v; c2a += bk*v;
    }
    c1p[tid] = c1a; c2p[tid] = c2a;
    __syncthreads();
    if (tid < DD) {
      ws[WS_C1 + ly*DD + tid] = c1p[tid] + c1p[tid+128];
      ws[WS_C2 + ly*DD + tid] = c2p[tid] + c2p[tid+128] + s4_inb[ly*DD + tid];
    }
    unsigned short* wgt = (unsigned short*)(ws + WS_WGT_F);
    for (int o = tid; o < DD*DD; o += 256) {
      int nn = o >> 7, k = o & 127;
      wgt[ly*DD*DD + o] = tile[k*136 + nn];                // 2-way bank (free), coalesced write
    }
    __syncthreads();
    for (int j = 0; j < 64; ++j) {
      int k = (tid >> 7) + 2*j;
      tile[k*136 + n] = f2b(s4_outW[((size_t)ly*DD + k)*DD + n]);
    }
    __syncthreads();
    unsigned short* wot = (unsigned short*)(ws + WS_WOT_F);
    for (int o = tid; o < DD*DD; o += 256) {
      int nn = o >> 7, k = o & 127;
      wot[ly*DD*DD + o] = tile[k*136 + nn];
    }
  } else if (blk < 27) {
    // ---- Toeplitz conv matrix for (ly,cx) ----
    __shared__ float part[256];
    __shared__ float kt[TAPS];
    int ly = (blk - 3) >> 3, cx = (blk - 3) & 7;
    int dt = tid & 31, nc = tid >> 5;
    const float* lre = lam_re + (ly*NCH + cx)*NST;
    const float* lim = lam_im + (ly*NCH + cx)*NST;
    const float* bn  = Bn  + (ly*NCH + cx)*NST;
    const float* cre = Cre + (ly*NCH + cx)*NST;
    const float* cim = Cim + (ly*NCH + cx)*NST;
    float td = (float)dt, acc = 0.f;
    for (int nn = nc*8; nn < nc*8 + 8; ++nn) {
      float e = expf(lre[nn]*td);
      float ang = lim[nn]*td;
      acc += bn[nn]*(cre[nn]*cosf(ang) - cim[nn]*sinf(ang))*e;
    }
    part[tid] = acc;
    __syncthreads();
    if (tid < 32) {
      float a = 0.f;
      #pragma unroll
      for (int i = 0; i < 8; ++i) a += part[i*32 + tid];
      kt[tid] = a;
    }
    __syncthreads();
    float dcv = Dc[ly*NCH + cx];
    unsigned short* tm = (unsigned short*)(ws + WS_TM_F) + (size_t)(ly*NCH + cx)*64*128;
    for (int o = tid; o < 64*128; o += 256) {
      int tl = o >> 7, j = o & 127;
      int m = j - tl - 1;
      float v = 0.f;
      if (m >= 0 && m < 64) {
        int idx = (m <= 31) ? (31 - m) : (m - 32);
        v = kt[idx];
      }
      if (j == tl + 32) v += dcv;
      tm[o] = f2b(v);
    }
  } else if (blk == 27) {
    // ---- BASE + GAW + ASCAL ----
    for (int o = tid; o < BB*DD; o += 256) {
      int b = o >> 7, d = o & 127;
      int sid = singer_id[b], lid = language_id[b];
      float acc = inb[d];
      for (int j = 0; j < 32; ++j) acc += singer_emb[sid*32 + j]*inW[(64 + j)*DD + d];
      for (int j = 0; j < 16; ++j) acc += lang_emb[lid*16 + j]*inW[(96 + j)*DD + d];
      ws[WS_BASE + o] = acc;
    }
    if (tid < DD) ws[WS_GAW + tid] = attn_g[tid]*attn_w[tid];
    if (tid == 0) {
      float c1s = 0.f, c2s = 0.f;
      for (int d = 0; d < DD; ++d) { c1s += attn_g[d]*attn_w[d]; c2s += attn_lnb[d]*attn_w[d]; }
      ws[WS_ASCAL+0] = c1s;
      ws[WS_ASCAL+1] = c2s + attn_bias[0];
    }
  } else {
    // ---- wo2t for head hd: [192n][64k] from genW_o[hd][64k][192n] via LDS ----
    __shared__ float gw[64*200];   // pad 200 (51.2KB)
    int hd = blk - 28;
    for (int k = 0; k < 64; ++k) {
      if (tid < 192) gw[k*200 + tid] = genW_o[((size_t)hd*64 + k)*192 + tid];
    }
    __syncthreads();
    unsigned short* wo2t = (unsigned short*)(ws + WS_WO2T_F);
    for (int o = tid; o < 192*64; o += 256) {
      int nn = o >> 6, k = o & 63;
      wo2t[(size_t)hd*192*64 + o] = f2b(gw[k*200 + nn]);
    }
  }
}

// ================= K1: embed + input proj + LN + SiLU -> h (fp32, buffer 0) =================
__global__ __launch_bounds__(256) void k1_input(
    const int* phone_seq, const float* f0, const float* phone_emb,
    const float* inW, const float* inln_g, const float* inln_b, float* ws)
{
  __shared__ __align__(16) float pm[64*72];
  __shared__ int   ps[64];
  __shared__ float fv[64];
  int tid = threadIdx.x;
  size_t gbase = (size_t)blockIdx.x * 64;
  if (tid < 64) { ps[tid] = phone_seq[gbase + tid]; fv[tid] = f0[gbase + tid]; }
  __syncthreads();
  #pragma unroll
  for (int j = 0; j < 4; ++j) {
    int idx4 = tid + 256*j;
    int tok = idx4 >> 4, col = idx4 & 15;
    float4 v = *(const float4*)(phone_emb + (size_t)ps[tok]*64 + col*4);
    *(float4*)(pm + tok*72 + col*4) = v;
  }
  __syncthreads();
  int ti = tid >> 5, di = tid & 31, d0 = di*4;
  float acc[8][4];
  #pragma unroll
  for (int i = 0; i < 8; ++i) { acc[i][0]=0.f; acc[i][1]=0.f; acc[i][2]=0.f; acc[i][3]=0.f; }
  for (int kk = 0; kk < 64; kk += 4) {
    float4 w0 = *(const float4*)(inW + (kk+0)*DD + d0);
    float4 w1 = *(const float4*)(inW + (kk+1)*DD + d0);
    float4 w2 = *(const float4*)(inW + (kk+2)*DD + d0);
    float4 w3 = *(const float4*)(inW + (kk+3)*DD + d0);
    #pragma unroll
    for (int i = 0; i < 8; ++i) {
      float4 a = *(float4*)(pm + (ti*8 + i)*72 + kk);
      acc[i][0] += a.x*w0.x + a.y*w1.x + a.z*w2.x + a.w*w3.x;
      acc[i][1] += a.x*w0.y + a.y*w1.y + a.z*w2.y + a.w*w3.y;
      acc[i][2] += a.x*w0.z + a.y*w1.z + a.z*w2.z + a.w*w3.z;
      acc[i][3] += a.x*w0.w + a.y*w1.w + a.z*w2.w + a.w*w3.w;
    }
  }
  float4 w112 = *(const float4*)(inW + 112*DD + d0);
  int b = (int)(gbase >> 13);
  float4 bs  = *(const float4*)(ws + WS_BASE + b*DD + d0);
  float4 lg4 = *(const float4*)(inln_g + d0);
  float4 lb4 = *(const float4*)(inln_b + d0);
  #pragma unroll
  for (int i = 0; i < 8; ++i) {
    int tok = ti*8 + i;
    float fz = fv[tok];
    float y0 = acc[i][0] + fz*w112.x + bs.x;
    float y1 = acc[i][1] + fz*w112.y + bs.y;
    float y2 = acc[i][2] + fz*w112.z + bs.z;
    float y3 = acc[i][3] + fz*w112.w + bs.w;
    float s  = y0+y1+y2+y3;
    float ss = y0*y0+y1*y1+y2*y2+y3*y3;
    #pragma unroll
    for (int m = 16; m >= 1; m >>= 1) { s += __shfl_xor(s, m); ss += __shfl_xor(ss, m); }
    float mean = s * 0.0078125f;
    float var  = ss * 0.0078125f - mean*mean;
    float rstd = rsqrtf(var + 1e-5f);
    y0 = silu_f((y0 - mean)*rstd*lg4.x + lb4.x);
    y1 = silu_f((y1 - mean)*rstd*lg4.y + lb4.y);
    y2 = silu_f((y2 - mean)*rstd*lg4.z + lb4.z);
    y3 = silu_f((y3 - mean)*rstd*lg4.w + lb4.w);
    *(float4*)(ws + WS_H + (gbase + tok)*DD + d0) = make_float4(y0,y1,y2,y3);
  }
}

// ================= K23 (fused path): LN+in_proj (halo recompute) + conv + out_proj per layer =====
// Reads hin (read-only), writes hout. z never leaves LDS. 1024 blocks, 64 out-tokens each.
__global__ __launch_bounds__(256) void k23_layer(
    float* ws, const float* s4_outb, int ly, int do_logits, size_t hin_ofs, size_t hout_ofs)
{
  __shared__ __align__(16) unsigned short zt[128*136];  // transposed z [ch][window-tok]
  __shared__ __align__(16) unsigned short ym[64*136];   // conv out bf16 A-tile
  __shared__ float rs_s[128], mrs_s[128];
  int tid = threadIdx.x, blk = blockIdx.x;
  int b = blk >> 7, t0 = (blk & 127) * 64;
  const float* hin = ws + hin_ofs + (size_t)b*LL*DD;
  // ---- LN stats over window [t0-32, t0+96) ----
  {
    float s[16], ss[16];
    #pragma unroll
    for (int j = 0; j < 16; ++j) {
      int idx4 = tid + 256*j;            // 128 tok x 32 float4
      int tok = idx4 >> 5, c4 = idx4 & 31;
      int t = t0 - 32 + tok;
      float4 v = make_float4(0.f,0.f,0.f,0.f);
      if (t >= 0 && t < LL) v = *(const float4*)(hin + (size_t)t*DD + c4*4);
      s[j]  = v.x+v.y+v.z+v.w;
      ss[j] = v.x*v.x+v.y*v.y+v.z*v.z+v.w*v.w;
    }
    #pragma unroll
    for (int m = 16; m >= 1; m >>= 1) {
      #pragma unroll
      for (int j = 0; j < 16; ++j) { s[j] += __shfl_xor(s[j], m); ss[j] += __shfl_xor(ss[j], m); }
    }
    if ((tid & 31) == 0) {
      #pragma unroll
      for (int j = 0; j < 16; ++j) {
        int tok = (tid >> 5) + 8*j;
        float mean = s[j]*0.0078125f;
        float var  = ss[j]*0.0078125f - mean*mean;
        float rstd = rsqrtf(var + 1e-5f);
        rs_s[tok] = rstd; mrs_s[tok] = mean*rstd;
      }
    }
  }
  __syncthreads();
  int w = tid >> 6, lane = tid & 63, q = lane >> 4, c = lane & 15;
  // ---- in_proj: wave w -> window rows [32w, 32w+32); A-frags straight from global h ----
  {
    const unsigned short* wgt = (const unsigned short*)(ws + WS_WGT_F) + ly*DD*DD;
    bf16x8 aF[2][4];
    float rsv[2][4], mrv[2][4];
    bool okr[2][4];
    #pragma unroll
    for (int mt = 0; mt < 2; ++mt) {
      int row = 32*w + mt*16 + c;
      int t = t0 - 32 + row;
      bool ok = (t >= 0 && t < LL);
      const float* hp = hin + (size_t)(ok ? t : 0)*DD;
      #pragma unroll
      for (int kk = 0; kk < 4; ++kk) {
        float4 u0 = make_float4(0.f,0.f,0.f,0.f), u1 = u0;
        if (ok) {
          u0 = *(const float4*)(hp + kk*32 + q*8);
          u1 = *(const float4*)(hp + kk*32 + q*8 + 4);
        }
        unsigned short tmp[8];
        tmp[0]=f2b(u0.x); tmp[1]=f2b(u0.y); tmp[2]=f2b(u0.z); tmp[3]=f2b(u0.w);
        tmp[4]=f2b(u1.x); tmp[5]=f2b(u1.y); tmp[6]=f2b(u1.z); tmp[7]=f2b(u1.w);
        aF[mt][kk] = *(bf16x8*)tmp;
      }
      #pragma unroll
      for (int r = 0; r < 4; ++r) {
        int rr = 32*w + mt*16 + q*4 + r;
        rsv[mt][r] = rs_s[rr]; mrv[mt][r] = mrs_s[rr];
        int tr = t0 - 32 + rr;
        okr[mt][r] = (tr >= 0 && tr < LL);
      }
    }
    #pragma unroll
    for (int mt = 0; mt < 2; ++mt) {
      #pragma unroll
      for (int nt = 0; nt < 8; ++nt) {
        f32x4 acc = {0.f,0.f,0.f,0.f};
        #pragma unroll
        for (int kk = 0; kk < 4; ++kk) {
          bf16x8 bF = *(const bf16x8*)(wgt + (nt*16 + c)*DD + kk*32 + q*8);
          acc = MFMA16(aF[mt][kk], bF, acc);
        }
        int col = nt*16 + c;
        float c1v = ws[WS_C1 + ly*DD + col];
        float c2v = ws[WS_C2 + ly*DD + col];
        us4 zp;
        {
          float z0 = okr[mt][0] ? (rsv[mt][0]*acc[0] - mrv[mt][0]*c1v + c2v) : 0.f;
          float z1 = okr[mt][1] ? (rsv[mt][1]*acc[1] - mrv[mt][1]*c1v + c2v) : 0.f;
          float z2 = okr[mt][2] ? (rsv[mt][2]*acc[2] - mrv[mt][2]*c1v + c2v) : 0.f;
          float z3 = okr[mt][3] ? (rsv[mt][3]*acc[3] - mrv[mt][3]*c1v + c2v) : 0.f;
          zp.x = f2b(z0); zp.y = f2b(z1); zp.z = f2b(z2); zp.w = f2b(z3);
        }
        *(us4*)(zt + col*136 + 32*w + mt*16 + q*4) = zp;   // transposed write, 2-way bank (free)
      }
    }
  }
  __syncthreads();
  // ---- conv via Toeplitz MFMA: output rows m16..m16+15 ----
  int m16 = w*16;
  {
    const unsigned short* tmat = (const unsigned short*)(ws + WS_TM_F) + (size_t)ly*NCH*64*128;
    #pragma unroll
    for (int cx = 0; cx < 8; ++cx) {
      int ch = cx*16 + c;
      f32x4 acc = {0.f,0.f,0.f,0.f};
      #pragma unroll
      for (int kk = 0; kk < 4; ++kk) {
        bf16x8 aT = *(const bf16x8*)(tmat + ((size_t)cx*64 + m16 + c)*128 + kk*32 + q*8);
        bf16x8 bZ = *(const bf16x8*)(zt + ch*136 + kk*32 + q*8);
        acc = MFMA16(aT, bZ, acc);
      }
      #pragma unroll
      for (int r = 0; r < 4; ++r)
        ym[(m16 + q*4 + r)*136 + ch] = f2b(acc[r]);
    }
  }
  __syncthreads();
  // ---- out_proj + SiLU + residual (+logits) ----
  const unsigned short* wot = (const unsigned short*)(ws + WS_WOT_F) + ly*DD*DD;
  bf16x8 aF[4];
  #pragma unroll
  for (int kk = 0; kk < 4; ++kk)
    aF[kk] = *(const bf16x8*)(ym + (m16 + c)*136 + kk*32 + q*8);
  const float* hrin = ws + hin_ofs;
  float* hout = ws + hout_ofs;
  float c1s = ws[WS_ASCAL+0], c2s = ws[WS_ASCAL+1];
  float sr[4] = {0,0,0,0}, ssr[4] = {0,0,0,0}, dtr[4] = {0,0,0,0};
  #pragma unroll
  for (int nt = 0; nt < 8; ++nt) {
    f32x4 acc = {0.f,0.f,0.f,0.f};
    #pragma unroll
    for (int kk = 0; kk < 4; ++kk) {
      bf16x8 bF = *(const bf16x8*)(wot + (nt*16 + c)*DD + kk*32 + q*8);
      acc = MFMA16(aF[kk], bF, acc);
    }
    int col = nt*16 + c;
    float ob = s4_outb[ly*DD + col];
    float gw = ws[WS_GAW + col];
    #pragma unroll
    for (int r = 0; r < 4; ++r) {
      size_t gofs = ((size_t)b*LL + t0 + m16 + q*4 + r)*DD + col;
      float hn = hrin[gofs] + silu_f(acc[r] + ob);
      hout[gofs] = hn;
      if (do_logits) { sr[r] += hn; ssr[r] += hn*hn; dtr[r] += hn*gw; }
    }
  }
  if (do_logits) {
    #pragma unroll
    for (int m = 8; m >= 1; m >>= 1) {
      #pragma unroll
      for (int r = 0; r < 4; ++r) {
        sr[r]  += __shfl_xor(sr[r],  m);
        ssr[r] += __shfl_xor(ssr[r], m);
        dtr[r] += __shfl_xor(dtr[r], m);
      }
    }
    if (c < 4) {
      int r = c;
      float mean = sr[r]*0.0078125f;
      float var  = ssr[r]*0.0078125f - mean*mean;
      float rstd = rsqrtf(var + 1e-5f);
      ws[WS_LOGITS + (size_t)b*LL + t0 + m16 + q*4 + r] = rstd*dtr[r] - mean*rstd*c1s + c2s;
    }
  }
}

// ================= K2 (fallback): folded LN + in_proj via MFMA -> z (bf16, TRANSPOSED [b][ch][t]) =====
__global__ __launch_bounds__(256) void k2_ln_inproj(float* ws, int ly)
{
  __shared__ __align__(16) unsigned short hm[64*136];
  __shared__ __align__(16) unsigned short zt_s[128*72];
  __shared__ float mrs_s[64], rs_s[64];
  int tid = threadIdx.x;
  size_t gbase = (size_t)blockIdx.x * 64;
  const float* hbuf = ws + WS_H;
  float s[8], ss[8];
  #pragma unroll
  for (int j = 0; j < 8; ++j) {
    int idx4 = tid + 256*j;
    int tok = idx4 >> 5, c4 = idx4 & 31;
    float4 v = *(const float4*)(hbuf + gbase*DD + (size_t)idx4*4);
    us4 p; p.x = f2b(v.x); p.y = f2b(v.y); p.z = f2b(v.z); p.w = f2b(v.w);
    *(us4*)(hm + tok*136 + c4*4) = p;
    s[j]  = v.x+v.y+v.z+v.w;
    ss[j] = v.x*v.x+v.y*v.y+v.z*v.z+v.w*v.w;
  }
  #pragma unroll
  for (int m = 16; m >= 1; m >>= 1) {
    #pragma unroll
    for (int j = 0; j < 8; ++j) { s[j] += __shfl_xor(s[j], m); ss[j] += __shfl_xor(ss[j], m); }
  }
  if ((tid & 31) == 0) {
    #pragma unroll
    for (int j = 0; j < 8; ++j) {
      int tok = (tid >> 5) + 8*j;
      float mean = s[j]*0.0078125f;
      float var  = ss[j]*0.0078125f - mean*mean;
      float rstd = rsqrtf(var + 1e-5f);
      rs_s[tok] = rstd; mrs_s[tok] = mean*rstd;
    }
  }
  __syncthreads();
  int w = tid >> 6, lane = tid & 63, q = lane >> 4, c = lane & 15;
  int m16 = w*16;
  const unsigned short* wgt = (const unsigned short*)(ws + WS_WGT_F) + ly*DD*DD;
  bf16x8 aF[4];
  #pragma unroll
  for (int kk = 0; kk < 4; ++kk)
    aF[kk] = *(const bf16x8*)(hm + (m16 + c)*136 + kk*32 + q*8);
  float rsv[4], mrv[4];
  #pragma unroll
  for (int r = 0; r < 4; ++r) { int row = m16 + q*4 + r; rsv[r] = rs_s[row]; mrv[r] = mrs_s[row]; }
  #pragma unroll
  for (int nt = 0; nt < 8; ++nt) {
    f32x4 acc = {0.f,0.f,0.f,0.f};
    #pragma unroll
    for (int kk = 0; kk < 4; ++kk) {
      bf16x8 bF = *(const bf16x8*)(wgt + (nt*16 + c)*DD + kk*32 + q*8);
      acc = MFMA16(aF[kk], bF, acc);
    }
    int col = nt*16 + c;
    float c1v = ws[WS_C1 + ly*DD + col];
    float c2v = ws[WS_C2 + ly*DD + col];
    #pragma unroll
    for (int r = 0; r < 4; ++r) {
      float zv = rsv[r]*acc[r] - mrv[r]*c1v + c2v;
      zt_s[col*72 + m16 + q*4 + r] = f2b(zv);
    }
  }
  __syncthreads();
  unsigned short* ztg = (unsigned short*)(ws + WS_ZB_F);
  int bb = (int)(gbase >> 13);
  int tb = (int)(gbase & 8191);
  #pragma unroll
  for (int it = 0; it < 4; ++it) {
    int o = tid + 256*it;
    int ch = o >> 3, tg = o & 7;
    bf16x8 v = *(const bf16x8*)(zt_s + ch*72 + tg*8);
    *(bf16x8*)(ztg + ((size_t)bb*DD + ch)*LL + tb + tg*8) = v;
  }
}

// ================= K3 (fallback): conv via MFMA (Toeplitz) + out_proj + residual (+logits) =====
__global__ __launch_bounds__(256) void k3_conv_out(
    float* ws, const float* s4_outb, int ly, int do_logits)
{
  __shared__ __align__(16) unsigned short zt[128*136];
  __shared__ __align__(16) unsigned short ym[64*136];
  int tid = threadIdx.x, blk = blockIdx.x;
  int b  = blk >> 7;
  int t0 = (blk & 127) * 64;
  const unsigned short* ztg = (const unsigned short*)(ws + WS_ZB_F);
  #pragma unroll
  for (int jj = 0; jj < 8; ++jj) {
    int o = tid + 256*jj;
    int ch = o >> 4, tg = o & 15;
    int t = t0 - 32 + tg*8;
    bf16x8 v = {0,0,0,0,0,0,0,0};
    if (t >= 0 && t < LL) v = *(const bf16x8*)(ztg + ((size_t)b*DD + ch)*LL + t);
    int sg = tg ^ ((ch >> 3) & 7);
    *(bf16x8*)(zt + ch*136 + sg*8) = v;
  }
  __syncthreads();
  int w = tid >> 6, lane = tid & 63, q = lane >> 4, c = lane & 15;
  int m16 = w*16;
  const unsigned short* tmat = (const unsigned short*)(ws + WS_TM_F) + (size_t)ly*NCH*64*128;
  #pragma unroll
  for (int cx = 0; cx < 8; ++cx) {
    int ch = cx*16 + c;
    int sw = (ch >> 3) & 7;
    f32x4 acc = {0.f,0.f,0.f,0.f};
    #pragma unroll
    for (int kk = 0; kk < 4; ++kk) {
      bf16x8 aF = *(const bf16x8*)(tmat + ((size_t)cx*64 + m16 + c)*128 + kk*32 + q*8);
      bf16x8 bF = *(const bf16x8*)(zt + ch*136 + ((kk*4 + q) ^ sw)*8);
      acc = MFMA16(aF, bF, acc);
    }
    #pragma unroll
    for (int r = 0; r < 4; ++r)
      ym[(m16 + q*4 + r)*136 + ch] = f2b(acc[r]);
  }
  __syncthreads();
  const unsigned short* wot = (const unsigned short*)(ws + WS_WOT_F) + ly*DD*DD;
  bf16x8 aF[4];
  #pragma unroll
  for (int kk = 0; kk < 4; ++kk)
    aF[kk] = *(const bf16x8*)(ym + (m16 + c)*136 + kk*32 + q*8);
  float* hbuf = ws + WS_H;
  float c1s = ws[WS_ASCAL+0], c2s = ws[WS_ASCAL+1];
  float sr[4] = {0,0,0,0}, ssr[4] = {0,0,0,0}, dtr[4] = {0,0,0,0};
  #pragma unroll
  for (int nt = 0; nt < 8; ++nt) {
    f32x4 acc = {0.f,0.f,0.f,0.f};
    #pragma unroll
    for (int kk = 0; kk < 4; ++kk) {
      bf16x8 bF = *(const bf16x8*)(wot + (nt*16 + c)*DD + kk*32 + q*8);
      acc = MFMA16(aF[kk], bF, acc);
    }
    int col = nt*16 + c;
    float ob = s4_outb[ly*DD + col];
    float gw = ws[WS_GAW + col];
    #pragma unroll
    for (int r = 0; r < 4; ++r) {
      size_t gofs = ((size_t)b*LL + t0 + m16 + q*4 + r)*DD + col;
      float hold = hbuf[gofs];
      float hn = hold + silu_f(acc[r] + ob);
      hbuf[gofs] = hn;
      if (do_logits) { sr[r] += hn; ssr[r] += hn*hn; dtr[r] += hn*gw; }
    }
  }
  if (do_logits) {
    #pragma unroll
    for (int m = 8; m >= 1; m >>= 1) {
      #pragma unroll
      for (int r = 0; r < 4; ++r) {
        sr[r]  += __shfl_xor(sr[r],  m);
        ssr[r] += __shfl_xor(ssr[r], m);
        dtr[r] += __shfl_xor(dtr[r], m);
      }
    }
    if (c < 4) {
      int r = c;
      float mean = sr[r]*0.0078125f;
      float var  = ssr[r]*0.0078125f - mean*mean;
      float rstd = rsqrtf(var + 1e-5f);
      ws[WS_LOGITS + (size_t)b*LL + t0 + m16 + q*4 + r] = rstd*dtr[r] - mean*rstd*c1s + c2s;
    }
  }
}

// ================= K5b: segmented softmax + weighted pool partials =================
__global__ __launch_bounds__(256) void k5b_pool(float* ws, size_t hofs)
{
  int blk = blockIdx.x, tid = threadIdx.x;
  int b = blk >> 4, seg = blk & 15;
  const float* lg = ws + WS_LOGITS + (size_t)b*LL + seg*512;
  __shared__ float ev[512];
  __shared__ float red[4], red2[4];
  __shared__ float vr[2][128];
  float a0 = lg[tid], a1 = lg[tid + 256];
  float mx = fmaxf(a0, a1);
  #pragma unroll
  for (int m = 32; m >= 1; m >>= 1) mx = fmaxf(mx, __shfl_xor(mx, m));
  if ((tid & 63) == 0) red[tid >> 6] = mx;
  __syncthreads();
  float M = fmaxf(fmaxf(red[0], red[1]), fmaxf(red[2], red[3]));
  float e0 = expf(a0 - M), e1 = expf(a1 - M);
  ev[tid] = e0; ev[tid + 256] = e1;
  float s = e0 + e1;
  #pragma unroll
  for (int m = 32; m >= 1; m >>= 1) s += __shfl_xor(s, m);
  if ((tid & 63) == 0) red2[tid >> 6] = s;
  __syncthreads();
  float S = red2[0] + red2[1] + red2[2] + red2[3];
  int ls = tid >> 7, d = tid & 127;
  const float* hb = ws + hofs + ((size_t)b*LL + seg*512)*DD;
  float acc = 0.f;
  for (int jj = 0; jj < 256; ++jj) {
    int tok = jj*2 + ls;
    acc += ev[tok] * hb[(size_t)tok*DD + d];
  }
  vr[ls][d] = acc;
  __syncthreads();
  if (tid < 128) ws[WS_SEGV + (size_t)(b*16 + seg)*DD + tid] = vr[0][tid] + vr[1][tid];
  if (tid == 0) { ws[WS_SEGM + b*16 + seg] = M; ws[WS_SEGS + b*16 + seg] = S; }
}

// ================= K5c: combine pool, g, FiLM scale/shift (grid 8, per batch) =================
__global__ __launch_bounds__(256) void k5c_cond(
    float* ws, const float* gpW, const float* gpb,
    const float* genW_s, const float* genb_s, const float* genW_sh, const float* genb_sh)
{
  __shared__ float wsg[16];
  __shared__ float Ssh[1];
  __shared__ float gpre[DD];
  __shared__ float red[256];
  __shared__ float gg[32];
  int b = blockIdx.x, tid = threadIdx.x;
  if (tid == 0) {
    float M = -1e30f;
    for (int sg = 0; sg < 16; ++sg) M = fmaxf(M, ws[WS_SEGM + b*16 + sg]);
    float S = 0.f;
    for (int sg = 0; sg < 16; ++sg) {
      float e = expf(ws[WS_SEGM + b*16 + sg] - M);
      wsg[sg] = e;
      S += ws[WS_SEGS + b*16 + sg]*e;
    }
    Ssh[0] = S;
  }
  __syncthreads();
  if (tid < DD) {
    float V = 0.f;
    #pragma unroll
    for (int sg = 0; sg < 16; ++sg)
      V += ws[WS_SEGV + (size_t)(b*16 + sg)*DD + tid]*wsg[sg];
    gpre[tid] = V / Ssh[0];
  }
  __syncthreads();
  {
    int c = tid & 31, kc = tid >> 5;   // 8 chunks x 16 k
    float p = 0.f;
    for (int k = kc*16; k < kc*16 + 16; ++k) p += gpre[k]*gpW[k*32 + c];
    red[tid] = p;
  }
  __syncthreads();
  if (tid < 32) {
    float a = gpb[tid];
    #pragma unroll
    for (int i = 0; i < 8; ++i) a += red[i*32 + tid];
    gg[tid] = a;
  }
  __syncthreads();
  for (int o = tid; o < 7*DD; o += 256) {
    int hd = o >> 7, d = o & 127;
    float sc = genb_s[hd*DD + d], sh = genb_sh[hd*DD + d];
    for (int c = 0; c < 32; ++c) {
      float g = gg[c];
      sc += g*genW_s[((size_t)hd*32 + c)*DD + d];
      sh += g*genW_sh[((size_t)hd*32 + c)*DD + d];
    }
    ws[WS_SCALE + (size_t)hd*BB*DD + b*DD + d] = sc;
    ws[WS_SHIFT + (size_t)hd*BB*DD + b*DD + d] = sh;
  }
}

// ================= K5d: build folded generator weights Wcat (bf16) + bias1 (grid 7, per head) =====
__global__ __launch_bounds__(256) void k5d_fold(float* ws, const float* genW_h, const float* genb_h)
{
  __shared__ float wh[128*65];   // [k][j], pad 65 -> conflict-free
  __shared__ float red[256];
  int hd = blockIdx.x, tid = threadIdx.x;
  for (int o = tid; o < DD*64; o += 256) {
    int k = o >> 6, j = o & 63;
    wh[k*65 + j] = genW_h[(size_t)hd*DD*64 + o];   // coalesced
  }
  __syncthreads();
  unsigned short* wct = (unsigned short*)(ws + WS_WCT_F);
  for (int b = 0; b < BB; ++b) {
    const float* sc = ws + WS_SCALE + (size_t)hd*BB*DD + b*DD;
    const float* sh = ws + WS_SHIFT + (size_t)hd*BB*DD + b*DD;
    for (int o = tid; o < 64*DD; o += 256) {
      int j = o >> 7, k = o & 127;
      wct[((size_t)b*448 + hd*64 + j)*DD + k] = f2b(sc[k]*wh[k*65 + j]);
    }
    {
      int j = tid >> 2, kc = tid & 3;   // 64 j x 4 chunks of 32 k
      float p = 0.f;
      for (int k = kc*32; k < kc*32 + 32; ++k) p += sh[k]*wh[k*65 + j];
      red[tid] = p;
      __syncthreads();
      if (tid < 64)
        ws[WS_BIAS1 + b*448 + hd*64 + tid] =
          genb_h[hd*64 + tid] + red[tid*4] + red[tid*4+1] + red[tid*4+2] + red[tid*4+3];
      __syncthreads();
    }
  }
}

// ================= K6: generator heads, 16-token tiles, LDS-staged coalesced output =================
__global__ __launch_bounds__(256) void k6_heads(float* ws, const float* genb_o, float* out, size_t hofs)
{
  __shared__ __align__(16) unsigned short hm[16*136];
  __shared__ __align__(16) unsigned short rm[16*456];
  __shared__ __align__(16) float om[16*NOUTD];
  int tid = threadIdx.x, blk = blockIdx.x;
  int b = blk >> 9, t0 = (blk & 511)*16;
  const float* hb = ws + hofs + ((size_t)b*LL + t0)*DD;
  #pragma unroll
  for (int j = 0; j < 2; ++j) {
    int idx4 = tid + 256*j;
    int tok = idx4 >> 5, c4 = idx4 & 31;
    float4 v = *(const float4*)(hb + (size_t)idx4*4);
    us4 p; p.x = f2b(v.x); p.y = f2b(v.y); p.z = f2b(v.z); p.w = f2b(v.w);
    *(us4*)(hm + tok*136 + c4*4) = p;
  }
  __syncthreads();
  int w = tid >> 6, lane = tid & 63, q = lane >> 4, c = lane & 15;
  {
    bf16x8 aF[4];
    #pragma unroll
    for (int kk = 0; kk < 4; ++kk)
      aF[kk] = *(const bf16x8*)(hm + c*136 + kk*32 + q*8);
    const unsigned short* wct = (const unsigned short*)(ws + WS_WCT_F) + (size_t)b*448*DD;
    for (int ntl = 0; ntl < 7; ++ntl) {
      int nt = w*7 + ntl;
      f32x4 acc = {0.f,0.f,0.f,0.f};
      #pragma unroll
      for (int kk = 0; kk < 4; ++kk) {
        bf16x8 bF = *(const bf16x8*)(wct + ((size_t)nt*16 + c)*DD + kk*32 + q*8);
        acc = MFMA16(aF[kk], bF, acc);
      }
      int col = nt*16 + c;
      float bias = ws[WS_BIAS1 + b*448 + col];
      #pragma unroll
      for (int r = 0; r < 4; ++r)
        rm[(q*4 + r)*456 + col] = f2b(silu_f(acc[r] + bias));
    }
  }
  __syncthreads();
  {
    const unsigned short* wo2t = (const unsigned short*)(ws + WS_WO2T_F);
    int i0 = w*7;
    int i1 = (i0 + 7 < 27) ? (i0 + 7) : 27;
    for (int i = i0; i < i1; ++i) {
      int hd = t_hd[i], nl = t_nl[i];
      bf16x8 aF0 = *(const bf16x8*)(rm + c*456 + hd*64 + q*8);
      bf16x8 aF1 = *(const bf16x8*)(rm + c*456 + hd*64 + 32 + q*8);
      f32x4 acc = {0.f,0.f,0.f,0.f};
      bf16x8 bF0 = *(const bf16x8*)(wo2t + ((size_t)hd*192 + nl*16 + c)*64 + q*8);
      bf16x8 bF1 = *(const bf16x8*)(wo2t + ((size_t)hd*192 + nl*16 + c)*64 + 32 + q*8);
      acc = MFMA16(aF0, bF0, acc);
      acc = MFMA16(aF1, bF1, acc);
      int cl = nl*16 + c;
      int di = c_dims_d[hd];
      if (cl < di) {
        float bo = genb_o[hd*192 + cl];
        #pragma unroll
        for (int r = 0; r < 4; ++r)
          om[(q*4 + r)*NOUTD + c_offs_d[hd] + cl] = acc[r] + bo;
      }
    }
  }
  __syncthreads();
  float* ob = out + ((size_t)b*LL + t0)*NOUTD;
  for (int o = tid; o < 1500; o += 256) {
    *(float4*)(ob + o*4) = *(const float4*)(om + o*4);
  }
}

// ================= launch =================
extern "C" void kernel_launch(void* const* d_in, const int* in_sizes, int n_in,
                              void* d_out, int out_size, void* d_ws, size_t ws_size,
                              hipStream_t stream) {
  const int*   phone_seq   = (const int*)  d_in[0];
  const int*   singer_id   = (const int*)  d_in[1];
  const int*   language_id = (const int*)  d_in[2];
  const float* f0          = (const float*)d_in[3];
  const float* phone_emb   = (const float*)d_in[4];
  const float* singer_emb  = (const float*)d_in[5];
  const float* lang_emb    = (const float*)d_in[6];
  const float* inW         = (const float*)d_in[7];
  const float* inb         = (const float*)d_in[8];
  const float* inln_g      = (const float*)d_in[9];
  const float* inln_b      = (const float*)d_in[10];
  const float* s4_ln_g     = (const float*)d_in[11];
  const float* s4_ln_b     = (const float*)d_in[12];
  const float* s4_inW      = (const float*)d_in[13];
  const float* s4_inb      = (const float*)d_in[14];
  const float* s4_outW     = (const float*)d_in[15];
  const float* s4_outb     = (const float*)d_in[16];
  const float* lam_re      = (const float*)d_in[17];
  const float* lam_im      = (const float*)d_in[18];
  const float* Bn          = (const float*)d_in[19];
  const float* C_re        = (const float*)d_in[20];
  const float* C_im        = (const float*)d_in[21];
  const float* Dc          = (const float*)d_in[22];
  const float* attn_g      = (const float*)d_in[23];
  const float* attn_lnb    = (const float*)d_in[24];
  const float* attn_w      = (const float*)d_in[25];
  const float* attn_bias   = (const float*)d_in[26];
  const float* gpW         = (const float*)d_in[27];
  const float* gpb         = (const float*)d_in[28];
  const float* genW_s      = (const float*)d_in[29];
  const float* genb_s      = (const float*)d_in[30];
  const float* genW_sh     = (const float*)d_in[31];
  const float* genb_sh     = (const float*)d_in[32];
  const float* genW_h      = (const float*)d_in[33];
  const float* genb_h      = (const float*)d_in[34];
  const float* genW_o      = (const float*)d_in[35];
  const float* genb_o      = (const float*)d_in[36];
  float* ws  = (float*)d_ws;
  float* out = (float*)d_out;

  bool fused = (ws_size >= WS_FUSED_END * sizeof(float));

  k0_setup<<<35, 256, 0, stream>>>(s4_ln_g, s4_ln_b, s4_inW, s4_inb, s4_outW,
                                   lam_re, lam_im, Bn, C_re, C_im,
                                   attn_g, attn_lnb, attn_w, attn_bias,
                                   singer_id, language_id, singer_emb, lang_emb, inW, inb,
                                   genW_o, Dc, ws);
  k1_input<<<BB*LL/64, 256, 0, stream>>>(phone_seq, f0, phone_emb, inW, inln_g, inln_b, ws);
  size_t hfin;
  if (fused) {
    k23_layer<<<BB*LL/64, 256, 0, stream>>>(ws, s4_outb, 0, 0, WS_H,  WS_H1);
    k23_layer<<<BB*LL/64, 256, 0, stream>>>(ws, s4_outb, 1, 0, WS_H1, WS_H);
    k23_layer<<<BB*LL/64, 256, 0, stream>>>(ws, s4_outb, 2, 1, WS_H,  WS_H1);
    hfin = WS_H1;
  } else {
    for (int ly = 0; ly < 3; ++ly) {
      k2_ln_inproj<<<BB*LL/64, 256, 0, stream>>>(ws, ly);
      k3_conv_out<<<BB*LL/64, 256, 0, stream>>>(ws, s4_outb, ly, (ly == 2) ? 1 : 0);
    }
    hfin = WS_H;
  }
  k5b_pool<<<BB*16, 256, 0, stream>>>(ws, hfin);
  k5c_cond<<<BB, 256, 0, stream>>>(ws, gpW, gpb, genW_s, genb_s, genW_sh, genb_sh);
  k5d_fold<<<7, 256, 0, stream>>>(ws, genW_h, genb_h);
  k6_heads<<<BB*LL/16, 256, 0, stream>>>(ws, genb_o, out, hfin);
}

// Round 6
// 677.923 us; speedup vs baseline: 1.0996x; 1.0996x over previous
//
#include <hip/hip_runtime.h>
#include <math.h>

// ---------------- problem constants ----------------
#define BB 8
#define LL 8192
#define DD 128
#define NCH 8
#define NST 64
#define TAPS 32          // e^{-0.5*32} ~ 1e-7 relative: FIR truncation far below threshold
#define NOUTD 375

// ---------------- MFMA types ----------------
typedef __attribute__((ext_vector_type(8))) short bf16x8;
typedef __attribute__((ext_vector_type(4))) float f32x4;
#define MFMA16(a,b,c) __builtin_amdgcn_mfma_f32_16x16x32_bf16((a),(b),(c),0,0,0)

struct __align__(8) us4 { unsigned short x,y,z,w; };

__device__ __forceinline__ unsigned short f2b(float f) {   // fp32 -> bf16 RNE
  unsigned x = __float_as_uint(f);
  unsigned r = (x + 0x7fffu + ((x >> 16) & 1u)) >> 16;
  return (unsigned short)r;
}
__device__ __forceinline__ float b2f(unsigned short u) {
  return __uint_as_float(((unsigned)u) << 16);
}
__device__ __forceinline__ float silu_f(float x){ return x / (1.f + expf(-x)); }

// ---------------- workspace layout (float offsets) ----------------
static constexpr size_t WS_H      = 0;                             // [B,L,128] fp32 residual
static constexpr size_t WS_LOGITS = WS_H      + (size_t)BB*LL*DD;  // [B,L]
static constexpr size_t WS_SEGM   = WS_LOGITS + (size_t)BB*LL;     // [B,16]
static constexpr size_t WS_SEGS   = WS_SEGM   + BB*16;             // [B,16]
static constexpr size_t WS_SEGV   = WS_SEGS   + BB*16;             // [B,16,128]
static constexpr size_t WS_SCALE  = WS_SEGV   + (size_t)BB*16*DD;  // [7,B,128]
static constexpr size_t WS_SHIFT  = WS_SCALE  + (size_t)7*BB*DD;   // [7,B,128]
static constexpr size_t WS_C1     = WS_SHIFT  + (size_t)7*BB*DD;   // [3,128]
static constexpr size_t WS_C2     = WS_C1     + 3*DD;              // [3,128]
static constexpr size_t WS_KTAB   = WS_C2     + 3*DD;              // [3,8,32]
static constexpr size_t WS_GAW    = WS_KTAB   + 3*NCH*TAPS;        // [128]
static constexpr size_t WS_ASCAL  = WS_GAW    + DD;                // 2 (+pad)
static constexpr size_t WS_BASE   = WS_ASCAL  + 32;                // [B,128]
static constexpr size_t WS_BIAS1  = WS_BASE   + BB*DD;             // [B,448] folded gen bias
// ----- ushort (bf16) regions, float-offset based -----
static constexpr size_t WS_ZB_F   = WS_BIAS1  + (size_t)BB*448;    // [B,L,128] bf16 z
static constexpr size_t WS_WGT_F  = WS_ZB_F   + (size_t)BB*LL*DD/2; // [3,128n,128k] bf16 ln-folded inW^T
static constexpr size_t WS_WOT_F  = WS_WGT_F  + (size_t)3*DD*DD/2;  // [3,128n,128k] bf16 outW^T
static constexpr size_t WS_WO2T_F = WS_WOT_F  + (size_t)3*DD*DD/2;  // [7,192n,64k] bf16 genW_o^T
static constexpr size_t WS_WCT_F  = WS_WO2T_F + (size_t)7*192*64/2; // [B,448n,128k] bf16 folded gen W
static constexpr size_t WS_TOTAL  = WS_WCT_F  + (size_t)BB*448*DD/2; // ~13.0M floats = 52 MB

__device__ __constant__ int c_offs_d[7] = {0, 1, 2, 102, 294, 358, 370};
__device__ __constant__ int c_dims_d[7] = {1, 1, 100, 192, 64, 12, 5};
// 27 n-tiles of GEMM2 (block-diagonal): (head, local col tile)
__device__ __constant__ int t_hd[27] = {0,1,2,2,2,2,2,2,2,3,3,3,3,3,3,3,3,3,3,3,3,4,4,4,4,5,6};
__device__ __constant__ int t_nl[27] = {0,0,0,1,2,3,4,5,6,0,1,2,3,4,5,6,7,8,9,10,11,0,1,2,3,0,0};

// ================= K0: fold weights, tabulate FIR taps, bf16 weight transposes =================
__global__ __launch_bounds__(256) void k0_setup(
    const float* s4_ln_g, const float* s4_ln_b, const float* s4_inW, const float* s4_inb,
    const float* s4_outW,
    const float* lam_re, const float* lam_im, const float* Bn, const float* Cre, const float* Cim,
    const float* attn_g, const float* attn_lnb, const float* attn_w, const float* attn_bias,
    const int* singer_id, const int* language_id,
    const float* singer_emb, const float* lang_emb, const float* inW, const float* inb,
    const float* genW_o, float* ws)
{
  int blk = blockIdx.x, tid = threadIdx.x;
  unsigned short* wgt  = (unsigned short*)(ws + WS_WGT_F);
  unsigned short* wot  = (unsigned short*)(ws + WS_WOT_F);
  unsigned short* wo2t = (unsigned short*)(ws + WS_WO2T_F);
  if (blk < 3) {
    int ly = blk;
    if (tid < DD) {
      int d = tid;
      float c1 = 0.f, c2 = 0.f;
      for (int k = 0; k < DD; ++k) {
        float g = s4_ln_g[ly*DD + k];
        float b = s4_ln_b[ly*DD + k];
        float w = s4_inW[((size_t)ly*DD + k)*DD + d];
        c1 += g * w;
        c2 += b * w;
      }
      ws[WS_C1 + ly*DD + d] = c1;
      ws[WS_C2 + ly*DD + d] = c2 + s4_inb[ly*DD + d];
    }
    // bf16 transposed weights: [n][k]
    for (int o = tid; o < DD*DD; o += 256) {
      int n = o >> 7, k = o & 127;
      wgt[ly*DD*DD + o] = f2b(s4_ln_g[ly*DD + k] * s4_inW[((size_t)ly*DD + k)*DD + n]);
      wot[ly*DD*DD + o] = f2b(s4_outW[((size_t)ly*DD + k)*DD + n]);
    }
    {  // FIR taps: 256 threads = 8 chunks x 32 taps
      int c = tid >> 5, dt = tid & 31;
      const float* lre = lam_re + (ly*NCH + c)*NST;
      const float* lim = lam_im + (ly*NCH + c)*NST;
      const float* bn  = Bn  + (ly*NCH + c)*NST;
      const float* cre = Cre + (ly*NCH + c)*NST;
      const float* cim = Cim + (ly*NCH + c)*NST;
      float td = (float)dt, acc = 0.f;
      for (int n = 0; n < NST; ++n) {
        float e = expf(lre[n]*td);
        float ang = lim[n]*td;
        acc += bn[n]*(cre[n]*cosf(ang) - cim[n]*sinf(ang))*e;
      }
      ws[WS_KTAB + (ly*NCH + c)*TAPS + dt] = acc;
    }
    if (ly == 0 && tid < DD) ws[WS_GAW + tid] = attn_g[tid]*attn_w[tid];
    if (ly == 0 && tid == 0) {
      float c1s = 0.f, c2s = 0.f;
      for (int d = 0; d < DD; ++d) { c1s += attn_g[d]*attn_w[d]; c2s += attn_lnb[d]*attn_w[d]; }
      ws[WS_ASCAL+0] = c1s;
      ws[WS_ASCAL+1] = c2s + attn_bias[0];
    }
  } else {
    for (int o = tid; o < BB*DD; o += 256) {
      int b = o >> 7, d = o & 127;
      int sid = singer_id[b], lid = language_id[b];
      float acc = inb[d];
      for (int j = 0; j < 32; ++j) acc += singer_emb[sid*32 + j]*inW[(64 + j)*DD + d];
      for (int j = 0; j < 16; ++j) acc += lang_emb[lid*16 + j]*inW[(96 + j)*DD + d];
      ws[WS_BASE + o] = acc;
    }
    // genW_o transposed bf16: wo2t[hd][n][k], n<192, k<64
    for (int o = tid; o < 7*192*64; o += 256) {
      int hd = o / (192*64), r = o % (192*64);
      int n = r >> 6, k = r & 63;
      wo2t[o] = f2b(genW_o[((size_t)hd*64 + k)*192 + n]);
    }
  }
}

// ================= K1: embed + input proj + LN + SiLU -> h (fp32) =================
__global__ __launch_bounds__(256) void k1_input(
    const int* phone_seq, const float* f0, const float* phone_emb,
    const float* inW, const float* inln_g, const float* inln_b, float* ws)
{
  __shared__ __align__(16) float pm[64*72];
  __shared__ int   ps[64];
  __shared__ float fv[64];
  int tid = threadIdx.x;
  size_t gbase = (size_t)blockIdx.x * 64;
  if (tid < 64) { ps[tid] = phone_seq[gbase + tid]; fv[tid] = f0[gbase + tid]; }
  __syncthreads();
  #pragma unroll
  for (int j = 0; j < 4; ++j) {
    int idx4 = tid + 256*j;
    int tok = idx4 >> 4, col = idx4 & 15;
    float4 v = *(const float4*)(phone_emb + (size_t)ps[tok]*64 + col*4);
    *(float4*)(pm + tok*72 + col*4) = v;
  }
  __syncthreads();
  int ti = tid >> 5, di = tid & 31, d0 = di*4;
  float acc[8][4];
  #pragma unroll
  for (int i = 0; i < 8; ++i) { acc[i][0]=0.f; acc[i][1]=0.f; acc[i][2]=0.f; acc[i][3]=0.f; }
  for (int kk = 0; kk < 64; kk += 4) {
    float4 w0 = *(const float4*)(inW + (kk+0)*DD + d0);
    float4 w1 = *(const float4*)(inW + (kk+1)*DD + d0);
    float4 w2 = *(const float4*)(inW + (kk+2)*DD + d0);
    float4 w3 = *(const float4*)(inW + (kk+3)*DD + d0);
    #pragma unroll
    for (int i = 0; i < 8; ++i) {
      float4 a = *(float4*)(pm + (ti*8 + i)*72 + kk);
      acc[i][0] += a.x*w0.x + a.y*w1.x + a.z*w2.x + a.w*w3.x;
      acc[i][1] += a.x*w0.y + a.y*w1.y + a.z*w2.y + a.w*w3.y;
      acc[i][2] += a.x*w0.z + a.y*w1.z + a.z*w2.z + a.w*w3.z;
      acc[i][3] += a.x*w0.w + a.y*w1.w + a.z*w2.w + a.w*w3.w;
    }
  }
  float4 w112 = *(const float4*)(inW + 112*DD + d0);
  int b = (int)(gbase >> 13);
  float4 bs  = *(const float4*)(ws + WS_BASE + b*DD + d0);
  float4 lg4 = *(const float4*)(inln_g + d0);
  float4 lb4 = *(const float4*)(inln_b + d0);
  #pragma unroll
  for (int i = 0; i < 8; ++i) {
    int tok = ti*8 + i;
    float fz = fv[tok];
    float y0 = acc[i][0] + fz*w112.x + bs.x;
    float y1 = acc[i][1] + fz*w112.y + bs.y;
    float y2 = acc[i][2] + fz*w112.z + bs.z;
    float y3 = acc[i][3] + fz*w112.w + bs.w;
    float s  = y0+y1+y2+y3;
    float ss = y0*y0+y1*y1+y2*y2+y3*y3;
    #pragma unroll
    for (int m = 16; m >= 1; m >>= 1) { s += __shfl_xor(s, m); ss += __shfl_xor(ss, m); }
    float mean = s * 0.0078125f;
    float var  = ss * 0.0078125f - mean*mean;
    float rstd = rsqrtf(var + 1e-5f);
    y0 = silu_f((y0 - mean)*rstd*lg4.x + lb4.x);
    y1 = silu_f((y1 - mean)*rstd*lg4.y + lb4.y);
    y2 = silu_f((y2 - mean)*rstd*lg4.z + lb4.z);
    y3 = silu_f((y3 - mean)*rstd*lg4.w + lb4.w);
    *(float4*)(ws + WS_H + (gbase + tok)*DD + d0) = make_float4(y0,y1,y2,y3);
  }
}

// ================= K2: folded LN + in_proj via MFMA -> z (bf16) =================
__global__ __launch_bounds__(256) void k2_ln_inproj(float* ws, int ly)
{
  __shared__ __align__(16) unsigned short hm[64*136];   // bf16 A-tile, stride 136 (bank-safe)
  __shared__ float mrs_s[64], rs_s[64];
  int tid = threadIdx.x;
  size_t gbase = (size_t)blockIdx.x * 64;
  const float* hbuf = ws + WS_H;
  float s[8], ss[8];
  #pragma unroll
  for (int j = 0; j < 8; ++j) {
    int idx4 = tid + 256*j;                 // 64 tok x 32 float4
    int tok = idx4 >> 5, c4 = idx4 & 31;
    float4 v = *(const float4*)(hbuf + gbase*DD + (size_t)idx4*4);
    us4 p; p.x = f2b(v.x); p.y = f2b(v.y); p.z = f2b(v.z); p.w = f2b(v.w);
    *(us4*)(hm + tok*136 + c4*4) = p;
    s[j]  = v.x+v.y+v.z+v.w;
    ss[j] = v.x*v.x+v.y*v.y+v.z*v.z+v.w*v.w;
  }
  #pragma unroll
  for (int m = 16; m >= 1; m >>= 1) {
    #pragma unroll
    for (int j = 0; j < 8; ++j) { s[j] += __shfl_xor(s[j], m); ss[j] += __shfl_xor(ss[j], m); }
  }
  if ((tid & 31) == 0) {
    #pragma unroll
    for (int j = 0; j < 8; ++j) {
      int tok = (tid >> 5) + 8*j;
      float mean = s[j]*0.0078125f;
      float var  = ss[j]*0.0078125f - mean*mean;
      float rstd = rsqrtf(var + 1e-5f);
      rs_s[tok] = rstd; mrs_s[tok] = mean*rstd;
    }
  }
  __syncthreads();
  int w = tid >> 6, lane = tid & 63, q = lane >> 4, c = lane & 15;
  int m16 = w*16;
  const unsigned short* wgt = (const unsigned short*)(ws + WS_WGT_F) + ly*DD*DD;
  bf16x8 aF[4];
  #pragma unroll
  for (int kk = 0; kk < 4; ++kk)
    aF[kk] = *(const bf16x8*)(hm + (m16 + c)*136 + kk*32 + q*8);
  float rsv[4], mrv[4];
  #pragma unroll
  for (int r = 0; r < 4; ++r) { int row = m16 + q*4 + r; rsv[r] = rs_s[row]; mrv[r] = mrs_s[row]; }
  unsigned short* zb = (unsigned short*)(ws + WS_ZB_F);
  #pragma unroll
  for (int nt = 0; nt < 8; ++nt) {
    f32x4 acc = {0.f,0.f,0.f,0.f};
    #pragma unroll
    for (int kk = 0; kk < 4; ++kk) {
      bf16x8 bF = *(const bf16x8*)(wgt + (nt*16 + c)*DD + kk*32 + q*8);
      acc = MFMA16(aF[kk], bF, acc);
    }
    int col = nt*16 + c;
    float c1v = ws[WS_C1 + ly*DD + col];
    float c2v = ws[WS_C2 + ly*DD + col];
    #pragma unroll
    for (int r = 0; r < 4; ++r) {
      float zv = rsv[r]*acc[r] - mrv[r]*c1v + c2v;
      zb[(gbase + m16 + q*4 + r)*DD + col] = f2b(zv);
    }
  }
}

// ================= K3: FIR conv (fp32) + skip + MFMA out_proj + SiLU + residual (+logits) =====
__global__ __launch_bounds__(256) void k3_conv_out(
    float* ws, const float* s4_outb, const float* Dc, int ly, int do_logits)
{
  __shared__ __align__(16) unsigned short zw[128*128];  // 64-tok tile + 32 halo each side (bf16)
  __shared__ __align__(16) unsigned short ym[64*136];   // bf16 A-tile for out_proj
  __shared__ float k2t[8*64];
  __shared__ float dcs[8];
  int tid = threadIdx.x, blk = blockIdx.x;
  int b  = blk >> 7;
  int t0 = (blk & 127) * 64;
  const unsigned short* zbp = (const unsigned short*)(ws + WS_ZB_F);
  #pragma unroll
  for (int j = 0; j < 8; ++j) {
    int idx8 = tid + 256*j;            // 128 tok x 16 ushort8
    int tok = idx8 >> 4, c8 = idx8 & 15;
    int t = t0 - 32 + tok;
    bf16x8 v = {0,0,0,0,0,0,0,0};
    if (t >= 0 && t < LL) v = *(const bf16x8*)(zbp + ((size_t)b*LL + t)*DD + c8*8);
    *(bf16x8*)(zw + tok*DD + c8*8) = v;
  }
  for (int o = tid; o < 512; o += 256) {     // K2[j]: j=-31..32 -> m=0..63
    int c = o >> 6, m = o & 63;
    int idx = (m <= 31) ? (31 - m) : (m - 32);
    k2t[o] = ws[WS_KTAB + (ly*NCH + c)*TAPS + idx];
  }
  if (tid < 8) dcs[tid] = Dc[ly*NCH + tid];
  __syncthreads();
  // conv: 2 passes, thread = (token half16, channel)
  #pragma unroll
  for (int p = 0; p < 2; ++p) {
    int half = p*2 + (tid >> 7), ch = tid & 127, cx = ch >> 4;
    int base = 1 + half*16;
    float ring[16], accv[16];
    #pragma unroll
    for (int x = 0; x < 16; ++x) { ring[x] = b2f(zw[(base + x)*DD + ch]); accv[x] = 0.f; }
    #pragma unroll
    for (int m = 0; m < 64; ++m) {
      float kf = k2t[cx*64 + m];
      #pragma unroll
      for (int i = 0; i < 16; ++i) accv[i] += kf * ring[(m + i) & 15];
      if (m < 63) ring[m & 15] = b2f(zw[(base + m + 16)*DD + ch]);
    }
    float dcv = dcs[cx];
    #pragma unroll
    for (int i = 0; i < 16; ++i) {
      int tl = half*16 + i;
      ym[tl*136 + ch] = f2b(accv[i] + dcv * b2f(zw[(32 + tl)*DD + ch]));
    }
  }
  __syncthreads();
  // MFMA out_proj: wave w -> rows w*16..+15
  int w = tid >> 6, lane = tid & 63, q = lane >> 4, c = lane & 15;
  int m16 = w*16;
  const unsigned short* wot = (const unsigned short*)(ws + WS_WOT_F) + ly*DD*DD;
  bf16x8 aF[4];
  #pragma unroll
  for (int kk = 0; kk < 4; ++kk)
    aF[kk] = *(const bf16x8*)(ym + (m16 + c)*136 + kk*32 + q*8);
  float* hbuf = ws + WS_H;
  float c1s = ws[WS_ASCAL+0], c2s = ws[WS_ASCAL+1];
  float sr[4] = {0,0,0,0}, ssr[4] = {0,0,0,0}, dtr[4] = {0,0,0,0};
  #pragma unroll
  for (int nt = 0; nt < 8; ++nt) {
    f32x4 acc = {0.f,0.f,0.f,0.f};
    #pragma unroll
    for (int kk = 0; kk < 4; ++kk) {
      bf16x8 bF = *(const bf16x8*)(wot + (nt*16 + c)*DD + kk*32 + q*8);
      acc = MFMA16(aF[kk], bF, acc);
    }
    int col = nt*16 + c;
    float ob = s4_outb[ly*DD + col];
    float gw = ws[WS_GAW + col];
    #pragma unroll
    for (int r = 0; r < 4; ++r) {
      size_t gofs = ((size_t)b*LL + t0 + m16 + q*4 + r)*DD + col;
      float hold = hbuf[gofs];
      float hn = hold + silu_f(acc[r] + ob);
      hbuf[gofs] = hn;
      if (do_logits) { sr[r] += hn; ssr[r] += hn*hn; dtr[r] += hn*gw; }
    }
  }
  if (do_logits) {
    #pragma unroll
    for (int m = 8; m >= 1; m >>= 1) {   // reduce across 16-lane quad (cols)
      #pragma unroll
      for (int r = 0; r < 4; ++r) {
        sr[r]  += __shfl_xor(sr[r],  m);
        ssr[r] += __shfl_xor(ssr[r], m);
        dtr[r] += __shfl_xor(dtr[r], m);
      }
    }
    if (c < 4) {
      int r = c;
      float mean = sr[r]*0.0078125f;
      float var  = ssr[r]*0.0078125f - mean*mean;
      float rstd = rsqrtf(var + 1e-5f);
      ws[WS_LOGITS + (size_t)b*LL + t0 + m16 + q*4 + r] = rstd*dtr[r] - mean*rstd*c1s + c2s;
    }
  }
}

// ================= K5b: segmented softmax + weighted pool partials =================
__global__ __launch_bounds__(256) void k5b_pool(float* ws)
{
  int blk = blockIdx.x, tid = threadIdx.x;
  int b = blk >> 4, seg = blk & 15;
  const float* lg = ws + WS_LOGITS + (size_t)b*LL + seg*512;
  __shared__ float ev[512];
  __shared__ float red[4], red2[4];
  __shared__ float vr[2][128];
  float a0 = lg[tid], a1 = lg[tid + 256];
  float mx = fmaxf(a0, a1);
  #pragma unroll
  for (int m = 32; m >= 1; m >>= 1) mx = fmaxf(mx, __shfl_xor(mx, m));
  if ((tid & 63) == 0) red[tid >> 6] = mx;
  __syncthreads();
  float M = fmaxf(fmaxf(red[0], red[1]), fmaxf(red[2], red[3]));
  float e0 = expf(a0 - M), e1 = expf(a1 - M);
  ev[tid] = e0; ev[tid + 256] = e1;
  float s = e0 + e1;
  #pragma unroll
  for (int m = 32; m >= 1; m >>= 1) s += __shfl_xor(s, m);
  if ((tid & 63) == 0) red2[tid >> 6] = s;
  __syncthreads();
  float S = red2[0] + red2[1] + red2[2] + red2[3];
  int ls = tid >> 7, d = tid & 127;
  const float* hb = ws + WS_H + ((size_t)b*LL + seg*512)*DD;
  float acc = 0.f;
  for (int jj = 0; jj < 256; ++jj) {
    int tok = jj*2 + ls;
    acc += ev[tok] * hb[(size_t)tok*DD + d];
  }
  vr[ls][d] = acc;
  __syncthreads();
  if (tid < 128) ws[WS_SEGV + (size_t)(b*16 + seg)*DD + tid] = vr[0][tid] + vr[1][tid];
  if (tid == 0) { ws[WS_SEGM + b*16 + seg] = M; ws[WS_SEGS + b*16 + seg] = S; }
}

// ================= K5c: combine pool, g, FiLM scale/shift (grid 8, per batch) =================
__global__ __launch_bounds__(256) void k5c_cond(
    float* ws, const float* gpW, const float* gpb,
    const float* genW_s, const float* genb_s, const float* genW_sh, const float* genb_sh)
{
  __shared__ float wsg[16];
  __shared__ float Ssh[1];
  __shared__ float gpre[DD];
  __shared__ float red[256];
  __shared__ float gg[32];
  int b = blockIdx.x, tid = threadIdx.x;
  if (tid == 0) {
    float M = -1e30f;
    for (int sg = 0; sg < 16; ++sg) M = fmaxf(M, ws[WS_SEGM + b*16 + sg]);
    float S = 0.f;
    for (int sg = 0; sg < 16; ++sg) {
      float e = expf(ws[WS_SEGM + b*16 + sg] - M);
      wsg[sg] = e;
      S += ws[WS_SEGS + b*16 + sg]*e;
    }
    Ssh[0] = S;
  }
  __syncthreads();
  if (tid < DD) {
    float V = 0.f;
    #pragma unroll
    for (int sg = 0; sg < 16; ++sg)
      V += ws[WS_SEGV + (size_t)(b*16 + sg)*DD + tid]*wsg[sg];
    gpre[tid] = V / Ssh[0];
  }
  __syncthreads();
  {
    int c = tid & 31, kc = tid >> 5;   // 8 chunks x 16 k
    float p = 0.f;
    for (int k = kc*16; k < kc*16 + 16; ++k) p += gpre[k]*gpW[k*32 + c];
    red[tid] = p;
  }
  __syncthreads();
  if (tid < 32) {
    float a = gpb[tid];
    #pragma unroll
    for (int i = 0; i < 8; ++i) a += red[i*32 + tid];
    gg[tid] = a;
  }
  __syncthreads();
  for (int o = tid; o < 7*DD; o += 256) {
    int hd = o >> 7, d = o & 127;
    float sc = genb_s[hd*DD + d], sh = genb_sh[hd*DD + d];
    for (int c = 0; c < 32; ++c) {
      float g = gg[c];
      sc += g*genW_s[((size_t)hd*32 + c)*DD + d];
      sh += g*genW_sh[((size_t)hd*32 + c)*DD + d];
    }
    ws[WS_SCALE + (size_t)hd*BB*DD + b*DD + d] = sc;
    ws[WS_SHIFT + (size_t)hd*BB*DD + b*DD + d] = sh;
  }
}

// ================= K5d: build folded generator weights Wcat (bf16) + bias1 =================
__global__ __launch_bounds__(256) void k5d_fold(float* ws, const float* genW_h, const float* genb_h)
{
  int blk = blockIdx.x, tid = threadIdx.x;
  int hd = blk >> 3, b = blk & 7;
  const float* sc = ws + WS_SCALE + (size_t)hd*BB*DD + b*DD;
  const float* sh = ws + WS_SHIFT + (size_t)hd*BB*DD + b*DD;
  const float* Wh = genW_h + (size_t)hd*DD*64;
  unsigned short* wct = (unsigned short*)(ws + WS_WCT_F);
  for (int o = tid; o < 64*DD; o += 256) {
    int j = o >> 7, k = o & 127;
    wct[((size_t)b*448 + hd*64 + j)*DD + k] = f2b(sc[k]*Wh[(size_t)k*64 + j]);
  }
  if (tid < 64) {
    int j = tid;
    float a = genb_h[hd*64 + j];
    for (int k = 0; k < DD; ++k) a += sh[k]*Wh[(size_t)k*64 + j];
    ws[WS_BIAS1 + b*448 + hd*64 + j] = a;
  }
}

// ================= K6: generator heads, M=64 tiles, 512 threads (4 m-tiles x 2 n-halves) =====
__global__ __launch_bounds__(512) void k6_heads(float* ws, const float* genb_o, float* out)
{
  __shared__ __align__(16) unsigned short hm[64*136];   // bf16 h tile (17.4 KB)
  __shared__ __align__(16) unsigned short rm[64*456];   // bf16 r tile (58.4 KB)
  int tid = threadIdx.x, blk = blockIdx.x;
  int b = blk >> 7, t0 = (blk & 127)*64;
  const float* hb = ws + WS_H + ((size_t)b*LL + t0)*DD;
  #pragma unroll
  for (int j = 0; j < 4; ++j) {
    int idx4 = tid + 512*j;                 // 64 tok x 32 float4
    int tok = idx4 >> 5, c4 = idx4 & 31;
    float4 v = *(const float4*)(hb + (size_t)idx4*4);
    us4 p; p.x = f2b(v.x); p.y = f2b(v.y); p.z = f2b(v.z); p.w = f2b(v.w);
    *(us4*)(hm + tok*136 + c4*4) = p;
  }
  __syncthreads();
  int w = tid >> 6, lane = tid & 63, q = lane >> 4, c = lane & 15;
  int mi = w & 3, nh = w >> 2;
  int m16 = mi*16;
  // ---- GEMM1: [64x128] @ Wcat_b^T[448][128] -> silu -> rm; wave (mi,nh): n-tiles nh*14..+13 ----
  {
    bf16x8 aF[4];
    #pragma unroll
    for (int kk = 0; kk < 4; ++kk)
      aF[kk] = *(const bf16x8*)(hm + (m16 + c)*136 + kk*32 + q*8);
    const unsigned short* wct = (const unsigned short*)(ws + WS_WCT_F) + (size_t)b*448*DD;
    #pragma unroll 2
    for (int ntl = 0; ntl < 14; ++ntl) {
      int nt = nh*14 + ntl;
      f32x4 acc = {0.f,0.f,0.f,0.f};
      #pragma unroll
      for (int kk = 0; kk < 4; ++kk) {
        bf16x8 bF = *(const bf16x8*)(wct + ((size_t)nt*16 + c)*DD + kk*32 + q*8);
        acc = MFMA16(aF[kk], bF, acc);
      }
      int col = nt*16 + c;
      float bias = ws[WS_BIAS1 + b*448 + col];
      #pragma unroll
      for (int r = 0; r < 4; ++r)
        rm[(m16 + q*4 + r)*456 + col] = f2b(silu_f(acc[r] + bias));
    }
  }
  __syncthreads();
  // ---- GEMM2: block-diagonal [64x448] @ Wo -> out [64x375]; wave (mi,nh): tiles of its half ----
  {
    const unsigned short* wo2t = (const unsigned short*)(ws + WS_WO2T_F);
    int i0 = (nh == 0) ? 0 : 14;
    int i1 = (nh == 0) ? 14 : 27;
    #pragma unroll 2
    for (int i = i0; i < i1; ++i) {
      int hd = t_hd[i], nl = t_nl[i];
      bf16x8 aF0 = *(const bf16x8*)(rm + (m16 + c)*456 + hd*64 + q*8);
      bf16x8 aF1 = *(const bf16x8*)(rm + (m16 + c)*456 + hd*64 + 32 + q*8);
      f32x4 acc = {0.f,0.f,0.f,0.f};
      bf16x8 bF0 = *(const bf16x8*)(wo2t + ((size_t)hd*192 + nl*16 + c)*64 + q*8);
      bf16x8 bF1 = *(const bf16x8*)(wo2t + ((size_t)hd*192 + nl*16 + c)*64 + 32 + q*8);
      acc = MFMA16(aF0, bF0, acc);
      acc = MFMA16(aF1, bF1, acc);
      int cl = nl*16 + c;
      int di = c_dims_d[hd];
      if (cl < di) {
        float bo = genb_o[hd*192 + cl];
        #pragma unroll
        for (int r = 0; r < 4; ++r)
          out[((size_t)b*LL + t0 + m16 + q*4 + r)*NOUTD + c_offs_d[hd] + cl] = acc[r] + bo;
      }
    }
  }
}

// ================= launch =================
extern "C" void kernel_launch(void* const* d_in, const int* in_sizes, int n_in,
                              void* d_out, int out_size, void* d_ws, size_t ws_size,
                              hipStream_t stream) {
  const int*   phone_seq   = (const int*)  d_in[0];
  const int*   singer_id   = (const int*)  d_in[1];
  const int*   language_id = (const int*)  d_in[2];
  const float* f0          = (const float*)d_in[3];
  const float* phone_emb   = (const float*)d_in[4];
  const float* singer_emb  = (const float*)d_in[5];
  const float* lang_emb    = (const float*)d_in[6];
  const float* inW         = (const float*)d_in[7];
  const float* inb         = (const float*)d_in[8];
  const float* inln_g      = (const float*)d_in[9];
  const float* inln_b      = (const float*)d_in[10];
  const float* s4_ln_g     = (const float*)d_in[11];
  const float* s4_ln_b     = (const float*)d_in[12];
  const float* s4_inW      = (const float*)d_in[13];
  const float* s4_inb      = (const float*)d_in[14];
  const float* s4_outW     = (const float*)d_in[15];
  const float* s4_outb     = (const float*)d_in[16];
  const float* lam_re      = (const float*)d_in[17];
  const float* lam_im      = (const float*)d_in[18];
  const float* Bn          = (const float*)d_in[19];
  const float* C_re        = (const float*)d_in[20];
  const float* C_im        = (const float*)d_in[21];
  const float* Dc          = (const float*)d_in[22];
  const float* attn_g      = (const float*)d_in[23];
  const float* attn_lnb    = (const float*)d_in[24];
  const float* attn_w      = (const float*)d_in[25];
  const float* attn_bias   = (const float*)d_in[26];
  const float* gpW         = (const float*)d_in[27];
  const float* gpb         = (const float*)d_in[28];
  const float* genW_s      = (const float*)d_in[29];
  const float* genb_s      = (const float*)d_in[30];
  const float* genW_sh     = (const float*)d_in[31];
  const float* genb_sh     = (const float*)d_in[32];
  const float* genW_h      = (const float*)d_in[33];
  const float* genb_h      = (const float*)d_in[34];
  const float* genW_o      = (const float*)d_in[35];
  const float* genb_o      = (const float*)d_in[36];
  float* ws  = (float*)d_ws;
  float* out = (float*)d_out;

  k0_setup<<<4, 256, 0, stream>>>(s4_ln_g, s4_ln_b, s4_inW, s4_inb, s4_outW,
                                  lam_re, lam_im, Bn, C_re, C_im,
                                  attn_g, attn_lnb, attn_w, attn_bias,
                                  singer_id, language_id, singer_emb, lang_emb, inW, inb,
                                  genW_o, ws);
  k1_input<<<BB*LL/64, 256, 0, stream>>>(phone_seq, f0, phone_emb, inW, inln_g, inln_b, ws);
  for (int ly = 0; ly < 3; ++ly) {
    k2_ln_inproj<<<BB*LL/64, 256, 0, stream>>>(ws, ly);
    k3_conv_out<<<BB*LL/64, 256, 0, stream>>>(ws, s4_outb, Dc, ly, (ly == 2) ? 1 : 0);
  }
  k5b_pool<<<BB*16, 256, 0, stream>>>(ws);
  k5c_cond<<<BB, 256, 0, stream>>>(ws, gpW, gpb, genW_s, genb_s, genW_sh, genb_sh);
  k5d_fold<<<56, 256, 0, stream>>>(ws, genW_h, genb_h);
  k6_heads<<<BB*LL/64, 512, 0, stream>>>(ws, genb_o, out);
}

// Round 7
// 629.496 us; speedup vs baseline: 1.1842x; 1.0769x over previous
//
#include <hip/hip_runtime.h>
#include <math.h>

// ---------------- problem constants ----------------
#define BB 8
#define LL 8192
#define DD 128
#define NCH 8
#define NST 64
#define TAPS 32          // e^{-0.5*32} ~ 1e-7 relative: FIR truncation far below threshold
#define NOUTD 375

// ---------------- MFMA types ----------------
typedef __attribute__((ext_vector_type(8))) short bf16x8;
typedef __attribute__((ext_vector_type(4))) float f32x4;
#define MFMA16(a,b,c) __builtin_amdgcn_mfma_f32_16x16x32_bf16((a),(b),(c),0,0,0)

struct __align__(8) us4 { unsigned short x,y,z,w; };

__device__ __forceinline__ unsigned short f2b(float f) {   // fp32 -> bf16 RNE
  unsigned x = __float_as_uint(f);
  unsigned r = (x + 0x7fffu + ((x >> 16) & 1u)) >> 16;
  return (unsigned short)r;
}
__device__ __forceinline__ float b2f(unsigned short u) {
  return __uint_as_float(((unsigned)u) << 16);
}
__device__ __forceinline__ float silu_f(float x){ return x / (1.f + expf(-x)); }

// ---------------- workspace layout (float offsets) ----------------
static constexpr size_t WS_H      = 0;                             // [B,L,128] fp32 residual
static constexpr size_t WS_LOGITS = WS_H      + (size_t)BB*LL*DD;  // [B,L]
static constexpr size_t WS_SEGM   = WS_LOGITS + (size_t)BB*LL;     // [B,16]
static constexpr size_t WS_SEGS   = WS_SEGM   + BB*16;             // [B,16]
static constexpr size_t WS_SEGV   = WS_SEGS   + BB*16;             // [B,16,128]
static constexpr size_t WS_SCALE  = WS_SEGV   + (size_t)BB*16*DD;  // [7,B,128]
static constexpr size_t WS_SHIFT  = WS_SCALE  + (size_t)7*BB*DD;   // [7,B,128]
static constexpr size_t WS_C1     = WS_SHIFT  + (size_t)7*BB*DD;   // [3,128]
static constexpr size_t WS_C2     = WS_C1     + 3*DD;              // [3,128]
static constexpr size_t WS_KTAB   = WS_C2     + 3*DD;              // [3,8,32]
static constexpr size_t WS_GAW    = WS_KTAB   + 3*NCH*TAPS;        // [128]
static constexpr size_t WS_ASCAL  = WS_GAW    + DD;                // 2 (+pad)
static constexpr size_t WS_BASE   = WS_ASCAL  + 32;                // [B,128]
static constexpr size_t WS_BIAS1  = WS_BASE   + BB*DD;             // [B,448] folded gen bias
// ----- ushort (bf16) regions, float-offset based -----
static constexpr size_t WS_ZB_F   = WS_BIAS1  + (size_t)BB*448;    // [B,L,128] bf16 z
static constexpr size_t WS_WGT_F  = WS_ZB_F   + (size_t)BB*LL*DD/2; // [3,128n,128k] bf16 ln-folded inW^T
static constexpr size_t WS_WOT_F  = WS_WGT_F  + (size_t)3*DD*DD/2;  // [3,128n,128k] bf16 outW^T
static constexpr size_t WS_WO2T_F = WS_WOT_F  + (size_t)3*DD*DD/2;  // [7,192n,64k] bf16 genW_o^T
static constexpr size_t WS_WCT_F  = WS_WO2T_F + (size_t)7*192*64/2; // [B,448n,128k] bf16 folded gen W
static constexpr size_t WS_TOTAL  = WS_WCT_F  + (size_t)BB*448*DD/2; // ~13.0M floats = 52 MB

__device__ __constant__ int c_offs_d[7] = {0, 1, 2, 102, 294, 358, 370};
__device__ __constant__ int c_dims_d[7] = {1, 1, 100, 192, 64, 12, 5};
// 27 n-tiles of GEMM2 (block-diagonal): (head, local col tile)
__device__ __constant__ int t_hd[27] = {0,1,2,2,2,2,2,2,2,3,3,3,3,3,3,3,3,3,3,3,3,4,4,4,4,5,6};
__device__ __constant__ int t_nl[27] = {0,0,0,1,2,3,4,5,6,0,1,2,3,4,5,6,7,8,9,10,11,0,1,2,3,0,0};

// ================= K0: fold weights, tabulate FIR taps, bf16 weight transposes =================
__global__ __launch_bounds__(256) void k0_setup(
    const float* s4_ln_g, const float* s4_ln_b, const float* s4_inW, const float* s4_inb,
    const float* s4_outW,
    const float* lam_re, const float* lam_im, const float* Bn, const float* Cre, const float* Cim,
    const float* attn_g, const float* attn_lnb, const float* attn_w, const float* attn_bias,
    const int* singer_id, const int* language_id,
    const float* singer_emb, const float* lang_emb, const float* inW, const float* inb,
    const float* genW_o, float* ws)
{
  int blk = blockIdx.x, tid = threadIdx.x;
  unsigned short* wgt  = (unsigned short*)(ws + WS_WGT_F);
  unsigned short* wot  = (unsigned short*)(ws + WS_WOT_F);
  unsigned short* wo2t = (unsigned short*)(ws + WS_WO2T_F);
  if (blk < 3) {
    int ly = blk;
    if (tid < DD) {
      int d = tid;
      float c1 = 0.f, c2 = 0.f;
      for (int k = 0; k < DD; ++k) {
        float g = s4_ln_g[ly*DD + k];
        float b = s4_ln_b[ly*DD + k];
        float w = s4_inW[((size_t)ly*DD + k)*DD + d];
        c1 += g * w;
        c2 += b * w;
      }
      ws[WS_C1 + ly*DD + d] = c1;
      ws[WS_C2 + ly*DD + d] = c2 + s4_inb[ly*DD + d];
    }
    // bf16 transposed weights: [n][k]
    for (int o = tid; o < DD*DD; o += 256) {
      int n = o >> 7, k = o & 127;
      wgt[ly*DD*DD + o] = f2b(s4_ln_g[ly*DD + k] * s4_inW[((size_t)ly*DD + k)*DD + n]);
      wot[ly*DD*DD + o] = f2b(s4_outW[((size_t)ly*DD + k)*DD + n]);
    }
    {  // FIR taps: 256 threads = 8 chunks x 32 taps
      int c = tid >> 5, dt = tid & 31;
      const float* lre = lam_re + (ly*NCH + c)*NST;
      const float* lim = lam_im + (ly*NCH + c)*NST;
      const float* bn  = Bn  + (ly*NCH + c)*NST;
      const float* cre = Cre + (ly*NCH + c)*NST;
      const float* cim = Cim + (ly*NCH + c)*NST;
      float td = (float)dt, acc = 0.f;
      for (int n = 0; n < NST; ++n) {
        float e = expf(lre[n]*td);
        float ang = lim[n]*td;
        acc += bn[n]*(cre[n]*cosf(ang) - cim[n]*sinf(ang))*e;
      }
      ws[WS_KTAB + (ly*NCH + c)*TAPS + dt] = acc;
    }
    if (ly == 0 && tid < DD) ws[WS_GAW + tid] = attn_g[tid]*attn_w[tid];
    if (ly == 0 && tid == 0) {
      float c1s = 0.f, c2s = 0.f;
      for (int d = 0; d < DD; ++d) { c1s += attn_g[d]*attn_w[d]; c2s += attn_lnb[d]*attn_w[d]; }
      ws[WS_ASCAL+0] = c1s;
      ws[WS_ASCAL+1] = c2s + attn_bias[0];
    }
  } else {
    for (int o = tid; o < BB*DD; o += 256) {
      int b = o >> 7, d = o & 127;
      int sid = singer_id[b], lid = language_id[b];
      float acc = inb[d];
      for (int j = 0; j < 32; ++j) acc += singer_emb[sid*32 + j]*inW[(64 + j)*DD + d];
      for (int j = 0; j < 16; ++j) acc += lang_emb[lid*16 + j]*inW[(96 + j)*DD + d];
      ws[WS_BASE + o] = acc;
    }
    // genW_o transposed bf16: wo2t[hd][n][k], n<192, k<64
    for (int o = tid; o < 7*192*64; o += 256) {
      int hd = o / (192*64), r = o % (192*64);
      int n = r >> 6, k = r & 63;
      wo2t[o] = f2b(genW_o[((size_t)hd*64 + k)*192 + n]);
    }
  }
}

// ================= K1p: embed + input proj + LN + SiLU -> h (fp32) + fused ly0 LN+in_proj -> z0 =====
__global__ __launch_bounds__(256) void k1p_input(
    const int* phone_seq, const float* f0, const float* phone_emb,
    const float* inW, const float* inln_g, const float* inln_b, float* ws)
{
  __shared__ __align__(16) float pm[64*72];
  __shared__ __align__(16) unsigned short hm[64*136];   // bf16 h tile for z0 MFMA
  __shared__ int   ps[64];
  __shared__ float fv[64];
  __shared__ float rs_s[64], mrs_s[64];
  int tid = threadIdx.x;
  size_t gbase = (size_t)blockIdx.x * 64;
  if (tid < 64) { ps[tid] = phone_seq[gbase + tid]; fv[tid] = f0[gbase + tid]; }
  __syncthreads();
  #pragma unroll
  for (int j = 0; j < 4; ++j) {
    int idx4 = tid + 256*j;
    int tok = idx4 >> 4, col = idx4 & 15;
    float4 v = *(const float4*)(phone_emb + (size_t)ps[tok]*64 + col*4);
    *(float4*)(pm + tok*72 + col*4) = v;
  }
  __syncthreads();
  int ti = tid >> 5, di = tid & 31, d0 = di*4;
  float acc[8][4];
  #pragma unroll
  for (int i = 0; i < 8; ++i) { acc[i][0]=0.f; acc[i][1]=0.f; acc[i][2]=0.f; acc[i][3]=0.f; }
  for (int kk = 0; kk < 64; kk += 4) {
    float4 w0 = *(const float4*)(inW + (kk+0)*DD + d0);
    float4 w1 = *(const float4*)(inW + (kk+1)*DD + d0);
    float4 w2 = *(const float4*)(inW + (kk+2)*DD + d0);
    float4 w3 = *(const float4*)(inW + (kk+3)*DD + d0);
    #pragma unroll
    for (int i = 0; i < 8; ++i) {
      float4 a = *(float4*)(pm + (ti*8 + i)*72 + kk);
      acc[i][0] += a.x*w0.x + a.y*w1.x + a.z*w2.x + a.w*w3.x;
      acc[i][1] += a.x*w0.y + a.y*w1.y + a.z*w2.y + a.w*w3.y;
      acc[i][2] += a.x*w0.z + a.y*w1.z + a.z*w2.z + a.w*w3.z;
      acc[i][3] += a.x*w0.w + a.y*w1.w + a.z*w2.w + a.w*w3.w;
    }
  }
  float4 w112 = *(const float4*)(inW + 112*DD + d0);
  int b = (int)(gbase >> 13);
  float4 bs  = *(const float4*)(ws + WS_BASE + b*DD + d0);
  float4 lg4 = *(const float4*)(inln_g + d0);
  float4 lb4 = *(const float4*)(inln_b + d0);
  float s2[8], ss2[8];
  #pragma unroll
  for (int i = 0; i < 8; ++i) {
    int tok = ti*8 + i;
    float fz = fv[tok];
    float y0 = acc[i][0] + fz*w112.x + bs.x;
    float y1 = acc[i][1] + fz*w112.y + bs.y;
    float y2 = acc[i][2] + fz*w112.z + bs.z;
    float y3 = acc[i][3] + fz*w112.w + bs.w;
    float s  = y0+y1+y2+y3;
    float ss = y0*y0+y1*y1+y2*y2+y3*y3;
    #pragma unroll
    for (int m = 16; m >= 1; m >>= 1) { s += __shfl_xor(s, m); ss += __shfl_xor(ss, m); }
    float mean = s * 0.0078125f;
    float var  = ss * 0.0078125f - mean*mean;
    float rstd = rsqrtf(var + 1e-5f);
    y0 = silu_f((y0 - mean)*rstd*lg4.x + lb4.x);
    y1 = silu_f((y1 - mean)*rstd*lg4.y + lb4.y);
    y2 = silu_f((y2 - mean)*rstd*lg4.z + lb4.z);
    y3 = silu_f((y3 - mean)*rstd*lg4.w + lb4.w);
    *(float4*)(ws + WS_H + (gbase + tok)*DD + d0) = make_float4(y0,y1,y2,y3);
    // stage bf16 tile + stats for z0
    us4 p; p.x = f2b(y0); p.y = f2b(y1); p.z = f2b(y2); p.w = f2b(y3);
    *(us4*)(hm + tok*136 + d0) = p;
    s2[i]  = y0+y1+y2+y3;
    ss2[i] = y0*y0+y1*y1+y2*y2+y3*y3;
  }
  #pragma unroll
  for (int m = 16; m >= 1; m >>= 1) {
    #pragma unroll
    for (int i = 0; i < 8; ++i) { s2[i] += __shfl_xor(s2[i], m); ss2[i] += __shfl_xor(ss2[i], m); }
  }
  if (di == 0) {
    #pragma unroll
    for (int i = 0; i < 8; ++i) {
      int tok = ti*8 + i;
      float mean = s2[i]*0.0078125f;
      float var  = ss2[i]*0.0078125f - mean*mean;
      float rstd = rsqrtf(var + 1e-5f);
      rs_s[tok] = rstd; mrs_s[tok] = mean*rstd;
    }
  }
  __syncthreads();
  // ---- z0 = folded-LN(h0) @ Wg0 via MFMA (verbatim k2 tail, ly=0) ----
  int w = tid >> 6, lane = tid & 63, q = lane >> 4, c = lane & 15;
  int m16 = w*16;
  const unsigned short* wgt = (const unsigned short*)(ws + WS_WGT_F);  // ly 0
  bf16x8 aF[4];
  #pragma unroll
  for (int kk = 0; kk < 4; ++kk)
    aF[kk] = *(const bf16x8*)(hm + (m16 + c)*136 + kk*32 + q*8);
  float rsv[4], mrv[4];
  #pragma unroll
  for (int r = 0; r < 4; ++r) { int row = m16 + q*4 + r; rsv[r] = rs_s[row]; mrv[r] = mrs_s[row]; }
  unsigned short* zb = (unsigned short*)(ws + WS_ZB_F);
  #pragma unroll
  for (int nt = 0; nt < 8; ++nt) {
    f32x4 za = {0.f,0.f,0.f,0.f};
    #pragma unroll
    for (int kk = 0; kk < 4; ++kk) {
      bf16x8 bF = *(const bf16x8*)(wgt + (nt*16 + c)*DD + kk*32 + q*8);
      za = MFMA16(aF[kk], bF, za);
    }
    int col = nt*16 + c;
    float c1v = ws[WS_C1 + col];
    float c2v = ws[WS_C2 + col];
    #pragma unroll
    for (int r = 0; r < 4; ++r) {
      float zv = rsv[r]*za[r] - mrv[r]*c1v + c2v;
      zb[(gbase + m16 + q*4 + r)*DD + col] = f2b(zv);
    }
  }
}

// ===== K3p: FIR conv + skip + MFMA out_proj + SiLU + residual (+logits) + fused next-layer LN+in_proj -> z(ly+1)
__global__ __launch_bounds__(256) void k3p_conv_out(
    float* ws, const float* s4_outb, const float* Dc, int ly, int do_logits, int do_z)
{
  __shared__ __align__(16) unsigned short zw[128*128];  // conv window; reused as hn bf16 tile after conv
  __shared__ __align__(16) unsigned short ym[64*136];   // bf16 A-tile for out_proj
  __shared__ float k2t[8*64];
  __shared__ float dcs[8];
  __shared__ float rs2[64], mrs2[64];
  int tid = threadIdx.x, blk = blockIdx.x;
  int b  = blk >> 7;
  int t0 = (blk & 127) * 64;
  const unsigned short* zbp = (const unsigned short*)(ws + WS_ZB_F);
  #pragma unroll
  for (int j = 0; j < 8; ++j) {
    int idx8 = tid + 256*j;            // 128 tok x 16 ushort8
    int tok = idx8 >> 4, c8 = idx8 & 15;
    int t = t0 - 32 + tok;
    bf16x8 v = {0,0,0,0,0,0,0,0};
    if (t >= 0 && t < LL) v = *(const bf16x8*)(zbp + ((size_t)b*LL + t)*DD + c8*8);
    *(bf16x8*)(zw + tok*DD + c8*8) = v;
  }
  for (int o = tid; o < 512; o += 256) {     // K2[j]: j=-31..32 -> m=0..63
    int c = o >> 6, m = o & 63;
    int idx = (m <= 31) ? (31 - m) : (m - 32);
    k2t[o] = ws[WS_KTAB + (ly*NCH + c)*TAPS + idx];
  }
  if (tid < 8) dcs[tid] = Dc[ly*NCH + tid];
  __syncthreads();
  // conv: 2 passes, thread = (token half16, channel)
  #pragma unroll
  for (int p = 0; p < 2; ++p) {
    int half = p*2 + (tid >> 7), ch = tid & 127, cx = ch >> 4;
    int base = 1 + half*16;
    float ring[16], accv[16];
    #pragma unroll
    for (int x = 0; x < 16; ++x) { ring[x] = b2f(zw[(base + x)*DD + ch]); accv[x] = 0.f; }
    #pragma unroll
    for (int m = 0; m < 64; ++m) {
      float kf = k2t[cx*64 + m];
      #pragma unroll
      for (int i = 0; i < 16; ++i) accv[i] += kf * ring[(m + i) & 15];
      if (m < 63) ring[m & 15] = b2f(zw[(base + m + 16)*DD + ch]);
    }
    float dcv = dcs[cx];
    #pragma unroll
    for (int i = 0; i < 16; ++i) {
      int tl = half*16 + i;
      ym[tl*136 + ch] = f2b(accv[i] + dcv * b2f(zw[(32 + tl)*DD + ch]));
    }
  }
  __syncthreads();
  // MFMA out_proj: wave w -> rows w*16..+15. After this sync zw is dead -> reuse as hn bf16 tile.
  unsigned short* hm2 = zw;   // [64][136] bf16 hn tile
  int w = tid >> 6, lane = tid & 63, q = lane >> 4, c = lane & 15;
  int m16 = w*16;
  const unsigned short* wot = (const unsigned short*)(ws + WS_WOT_F) + ly*DD*DD;
  bf16x8 aF[4];
  #pragma unroll
  for (int kk = 0; kk < 4; ++kk)
    aF[kk] = *(const bf16x8*)(ym + (m16 + c)*136 + kk*32 + q*8);
  float* hbuf = ws + WS_H;
  float c1s = ws[WS_ASCAL+0], c2s = ws[WS_ASCAL+1];
  float sr[4] = {0,0,0,0}, ssr[4] = {0,0,0,0}, dtr[4] = {0,0,0,0};
  #pragma unroll
  for (int nt = 0; nt < 8; ++nt) {
    f32x4 acc = {0.f,0.f,0.f,0.f};
    #pragma unroll
    for (int kk = 0; kk < 4; ++kk) {
      bf16x8 bF = *(const bf16x8*)(wot + (nt*16 + c)*DD + kk*32 + q*8);
      acc = MFMA16(aF[kk], bF, acc);
    }
    int col = nt*16 + c;
    float ob = s4_outb[ly*DD + col];
    float gw = ws[WS_GAW + col];
    #pragma unroll
    for (int r = 0; r < 4; ++r) {
      size_t gofs = ((size_t)b*LL + t0 + m16 + q*4 + r)*DD + col;
      float hold = hbuf[gofs];
      float hn = hold + silu_f(acc[r] + ob);
      hbuf[gofs] = hn;
      hm2[(m16 + q*4 + r)*136 + col] = f2b(hn);
      sr[r] += hn; ssr[r] += hn*hn;
      if (do_logits) dtr[r] += hn*gw;
    }
  }
  // per-row stats over the 16 c-lanes (each lane covers 8 cols -> 128 total)
  #pragma unroll
  for (int m = 8; m >= 1; m >>= 1) {
    #pragma unroll
    for (int r = 0; r < 4; ++r) {
      sr[r]  += __shfl_xor(sr[r],  m);
      ssr[r] += __shfl_xor(ssr[r], m);
      if (do_logits) dtr[r] += __shfl_xor(dtr[r], m);
    }
  }
  if (c < 4) {
    int r = c;
    float mean = sr[r]*0.0078125f;
    float var  = ssr[r]*0.0078125f - mean*mean;
    float rstd = rsqrtf(var + 1e-5f);
    int row = m16 + q*4 + r;
    if (do_z) { rs2[row] = rstd; mrs2[row] = mean*rstd; }
    if (do_logits)
      ws[WS_LOGITS + (size_t)b*LL + t0 + row] = rstd*dtr[r] - mean*rstd*c1s + c2s;
  }
  if (do_z) {
    __syncthreads();
    // ---- z(ly+1) = folded-LN(hn) @ Wg(ly+1) via MFMA (verbatim k2 tail) ----
    const unsigned short* wgt2 = (const unsigned short*)(ws + WS_WGT_F) + (ly+1)*DD*DD;
    bf16x8 aF2[4];
    #pragma unroll
    for (int kk = 0; kk < 4; ++kk)
      aF2[kk] = *(const bf16x8*)(hm2 + (m16 + c)*136 + kk*32 + q*8);
    float rsv[4], mrv[4];
    #pragma unroll
    for (int r = 0; r < 4; ++r) { int row = m16 + q*4 + r; rsv[r] = rs2[row]; mrv[r] = mrs2[row]; }
    unsigned short* zb = (unsigned short*)(ws + WS_ZB_F);
    size_t gbase = (size_t)b*LL + t0;
    #pragma unroll
    for (int nt = 0; nt < 8; ++nt) {
      f32x4 za = {0.f,0.f,0.f,0.f};
      #pragma unroll
      for (int kk = 0; kk < 4; ++kk) {
        bf16x8 bF = *(const bf16x8*)(wgt2 + (nt*16 + c)*DD + kk*32 + q*8);
        za = MFMA16(aF2[kk], bF, za);
      }
      int col = nt*16 + c;
      float c1v = ws[WS_C1 + (ly+1)*DD + col];
      float c2v = ws[WS_C2 + (ly+1)*DD + col];
      #pragma unroll
      for (int r = 0; r < 4; ++r) {
        float zv = rsv[r]*za[r] - mrv[r]*c1v + c2v;
        zb[(gbase + m16 + q*4 + r)*DD + col] = f2b(zv);
      }
    }
  }
}

// ================= K5b: segmented softmax + weighted pool partials =================
__global__ __launch_bounds__(256) void k5b_pool(float* ws)
{
  int blk = blockIdx.x, tid = threadIdx.x;
  int b = blk >> 4, seg = blk & 15;
  const float* lg = ws + WS_LOGITS + (size_t)b*LL + seg*512;
  __shared__ float ev[512];
  __shared__ float red[4], red2[4];
  __shared__ float vr[2][128];
  float a0 = lg[tid], a1 = lg[tid + 256];
  float mx = fmaxf(a0, a1);
  #pragma unroll
  for (int m = 32; m >= 1; m >>= 1) mx = fmaxf(mx, __shfl_xor(mx, m));
  if ((tid & 63) == 0) red[tid >> 6] = mx;
  __syncthreads();
  float M = fmaxf(fmaxf(red[0], red[1]), fmaxf(red[2], red[3]));
  float e0 = expf(a0 - M), e1 = expf(a1 - M);
  ev[tid] = e0; ev[tid + 256] = e1;
  float s = e0 + e1;
  #pragma unroll
  for (int m = 32; m >= 1; m >>= 1) s += __shfl_xor(s, m);
  if ((tid & 63) == 0) red2[tid >> 6] = s;
  __syncthreads();
  float S = red2[0] + red2[1] + red2[2] + red2[3];
  int ls = tid >> 7, d = tid & 127;
  const float* hb = ws + WS_H + ((size_t)b*LL + seg*512)*DD;
  float acc = 0.f;
  for (int jj = 0; jj < 256; ++jj) {
    int tok = jj*2 + ls;
    acc += ev[tok] * hb[(size_t)tok*DD + d];
  }
  vr[ls][d] = acc;
  __syncthreads();
  if (tid < 128) ws[WS_SEGV + (size_t)(b*16 + seg)*DD + tid] = vr[0][tid] + vr[1][tid];
  if (tid == 0) { ws[WS_SEGM + b*16 + seg] = M; ws[WS_SEGS + b*16 + seg] = S; }
}

// ================= K5c: combine pool, g, FiLM scale/shift (grid 8, per batch) =================
__global__ __launch_bounds__(256) void k5c_cond(
    float* ws, const float* gpW, const float* gpb,
    const float* genW_s, const float* genb_s, const float* genW_sh, const float* genb_sh)
{
  __shared__ float wsg[16];
  __shared__ float Ssh[1];
  __shared__ float gpre[DD];
  __shared__ float red[256];
  __shared__ float gg[32];
  int b = blockIdx.x, tid = threadIdx.x;
  if (tid == 0) {
    float M = -1e30f;
    for (int sg = 0; sg < 16; ++sg) M = fmaxf(M, ws[WS_SEGM + b*16 + sg]);
    float S = 0.f;
    for (int sg = 0; sg < 16; ++sg) {
      float e = expf(ws[WS_SEGM + b*16 + sg] - M);
      wsg[sg] = e;
      S += ws[WS_SEGS + b*16 + sg]*e;
    }
    Ssh[0] = S;
  }
  __syncthreads();
  if (tid < DD) {
    float V = 0.f;
    #pragma unroll
    for (int sg = 0; sg < 16; ++sg)
      V += ws[WS_SEGV + (size_t)(b*16 + sg)*DD + tid]*wsg[sg];
    gpre[tid] = V / Ssh[0];
  }
  __syncthreads();
  {
    int c = tid & 31, kc = tid >> 5;   // 8 chunks x 16 k
    float p = 0.f;
    for (int k = kc*16; k < kc*16 + 16; ++k) p += gpre[k]*gpW[k*32 + c];
    red[tid] = p;
  }
  __syncthreads();
  if (tid < 32) {
    float a = gpb[tid];
    #pragma unroll
    for (int i = 0; i < 8; ++i) a += red[i*32 + tid];
    gg[tid] = a;
  }
  __syncthreads();
  for (int o = tid; o < 7*DD; o += 256) {
    int hd = o >> 7, d = o & 127;
    float sc = genb_s[hd*DD + d], sh = genb_sh[hd*DD + d];
    for (int c = 0; c < 32; ++c) {
      float g = gg[c];
      sc += g*genW_s[((size_t)hd*32 + c)*DD + d];
      sh += g*genW_sh[((size_t)hd*32 + c)*DD + d];
    }
    ws[WS_SCALE + (size_t)hd*BB*DD + b*DD + d] = sc;
    ws[WS_SHIFT + (size_t)hd*BB*DD + b*DD + d] = sh;
  }
}

// ================= K5d: build folded generator weights Wcat (bf16) + bias1 =================
__global__ __launch_bounds__(256) void k5d_fold(float* ws, const float* genW_h, const float* genb_h)
{
  int blk = blockIdx.x, tid = threadIdx.x;
  int hd = blk >> 3, b = blk & 7;
  const float* sc = ws + WS_SCALE + (size_t)hd*BB*DD + b*DD;
  const float* sh = ws + WS_SHIFT + (size_t)hd*BB*DD + b*DD;
  const float* Wh = genW_h + (size_t)hd*DD*64;
  unsigned short* wct = (unsigned short*)(ws + WS_WCT_F);
  for (int o = tid; o < 64*DD; o += 256) {
    int j = o >> 7, k = o & 127;
    wct[((size_t)b*448 + hd*64 + j)*DD + k] = f2b(sc[k]*Wh[(size_t)k*64 + j]);
  }
  if (tid < 64) {
    int j = tid;
    float a = genb_h[hd*64 + j];
    for (int k = 0; k < DD; ++k) a += sh[k]*Wh[(size_t)k*64 + j];
    ws[WS_BIAS1 + b*448 + hd*64 + j] = a;
  }
}

// ================= K6: generator heads, M=64 tiles, 512 threads (4 m-tiles x 2 n-halves) =====
__global__ __launch_bounds__(512) void k6_heads(float* ws, const float* genb_o, float* out)
{
  __shared__ __align__(16) unsigned short hm[64*136];   // bf16 h tile (17.4 KB)
  __shared__ __align__(16) unsigned short rm[64*456];   // bf16 r tile (58.4 KB)
  int tid = threadIdx.x, blk = blockIdx.x;
  int b = blk >> 7, t0 = (blk & 127)*64;
  const float* hb = ws + WS_H + ((size_t)b*LL + t0)*DD;
  #pragma unroll
  for (int j = 0; j < 4; ++j) {
    int idx4 = tid + 512*j;                 // 64 tok x 32 float4
    int tok = idx4 >> 5, c4 = idx4 & 31;
    float4 v = *(const float4*)(hb + (size_t)idx4*4);
    us4 p; p.x = f2b(v.x); p.y = f2b(v.y); p.z = f2b(v.z); p.w = f2b(v.w);
    *(us4*)(hm + tok*136 + c4*4) = p;
  }
  __syncthreads();
  int w = tid >> 6, lane = tid & 63, q = lane >> 4, c = lane & 15;
  int mi = w & 3, nh = w >> 2;
  int m16 = mi*16;
  // ---- GEMM1: [64x128] @ Wcat_b^T[448][128] -> silu -> rm; wave (mi,nh): n-tiles nh*14..+13 ----
  {
    bf16x8 aF[4];
    #pragma unroll
    for (int kk = 0; kk < 4; ++kk)
      aF[kk] = *(const bf16x8*)(hm + (m16 + c)*136 + kk*32 + q*8);
    const unsigned short* wct = (const unsigned short*)(ws + WS_WCT_F) + (size_t)b*448*DD;
    #pragma unroll 2
    for (int ntl = 0; ntl < 14; ++ntl) {
      int nt = nh*14 + ntl;
      f32x4 acc = {0.f,0.f,0.f,0.f};
      #pragma unroll
      for (int kk = 0; kk < 4; ++kk) {
        bf16x8 bF = *(const bf16x8*)(wct + ((size_t)nt*16 + c)*DD + kk*32 + q*8);
        acc = MFMA16(aF[kk], bF, acc);
      }
      int col = nt*16 + c;
      float bias = ws[WS_BIAS1 + b*448 + col];
      #pragma unroll
      for (int r = 0; r < 4; ++r)
        rm[(m16 + q*4 + r)*456 + col] = f2b(silu_f(acc[r] + bias));
    }
  }
  __syncthreads();
  // ---- GEMM2: block-diagonal [64x448] @ Wo -> out [64x375]; wave (mi,nh): tiles of its half ----
  {
    const unsigned short* wo2t = (const unsigned short*)(ws + WS_WO2T_F);
    int i0 = (nh == 0) ? 0 : 14;
    int i1 = (nh == 0) ? 14 : 27;
    #pragma unroll 2
    for (int i = i0; i < i1; ++i) {
      int hd = t_hd[i], nl = t_nl[i];
      bf16x8 aF0 = *(const bf16x8*)(rm + (m16 + c)*456 + hd*64 + q*8);
      bf16x8 aF1 = *(const bf16x8*)(rm + (m16 + c)*456 + hd*64 + 32 + q*8);
      f32x4 acc = {0.f,0.f,0.f,0.f};
      bf16x8 bF0 = *(const bf16x8*)(wo2t + ((size_t)hd*192 + nl*16 + c)*64 + q*8);
      bf16x8 bF1 = *(const bf16x8*)(wo2t + ((size_t)hd*192 + nl*16 + c)*64 + 32 + q*8);
      acc = MFMA16(aF0, bF0, acc);
      acc = MFMA16(aF1, bF1, acc);
      int cl = nl*16 + c;
      int di = c_dims_d[hd];
      if (cl < di) {
        float bo = genb_o[hd*192 + cl];
        #pragma unroll
        for (int r = 0; r < 4; ++r)
          out[((size_t)b*LL + t0 + m16 + q*4 + r)*NOUTD + c_offs_d[hd] + cl] = acc[r] + bo;
      }
    }
  }
}

// ================= launch =================
extern "C" void kernel_launch(void* const* d_in, const int* in_sizes, int n_in,
                              void* d_out, int out_size, void* d_ws, size_t ws_size,
                              hipStream_t stream) {
  const int*   phone_seq   = (const int*)  d_in[0];
  const int*   singer_id   = (const int*)  d_in[1];
  const int*   language_id = (const int*)  d_in[2];
  const float* f0          = (const float*)d_in[3];
  const float* phone_emb   = (const float*)d_in[4];
  const float* singer_emb  = (const float*)d_in[5];
  const float* lang_emb    = (const float*)d_in[6];
  const float* inW         = (const float*)d_in[7];
  const float* inb         = (const float*)d_in[8];
  const float* inln_g      = (const float*)d_in[9];
  const float* inln_b      = (const float*)d_in[10];
  const float* s4_ln_g     = (const float*)d_in[11];
  const float* s4_ln_b     = (const float*)d_in[12];
  const float* s4_inW      = (const float*)d_in[13];
  const float* s4_inb      = (const float*)d_in[14];
  const float* s4_outW     = (const float*)d_in[15];
  const float* s4_outb     = (const float*)d_in[16];
  const float* lam_re      = (const float*)d_in[17];
  const float* lam_im      = (const float*)d_in[18];
  const float* Bn          = (const float*)d_in[19];
  const float* C_re        = (const float*)d_in[20];
  const float* C_im        = (const float*)d_in[21];
  const float* Dc          = (const float*)d_in[22];
  const float* attn_g      = (const float*)d_in[23];
  const float* attn_lnb    = (const float*)d_in[24];
  const float* attn_w      = (const float*)d_in[25];
  const float* attn_bias   = (const float*)d_in[26];
  const float* gpW         = (const float*)d_in[27];
  const float* gpb         = (const float*)d_in[28];
  const float* genW_s      = (const float*)d_in[29];
  const float* genb_s      = (const float*)d_in[30];
  const float* genW_sh     = (const float*)d_in[31];
  const float* genb_sh     = (const float*)d_in[32];
  const float* genW_h      = (const float*)d_in[33];
  const float* genb_h      = (const float*)d_in[34];
  const float* genW_o      = (const float*)d_in[35];
  const float* genb_o      = (const float*)d_in[36];
  float* ws  = (float*)d_ws;
  float* out = (float*)d_out;

  k0_setup<<<4, 256, 0, stream>>>(s4_ln_g, s4_ln_b, s4_inW, s4_inb, s4_outW,
                                  lam_re, lam_im, Bn, C_re, C_im,
                                  attn_g, attn_lnb, attn_w, attn_bias,
                                  singer_id, language_id, singer_emb, lang_emb, inW, inb,
                                  genW_o, ws);
  k1p_input<<<BB*LL/64, 256, 0, stream>>>(phone_seq, f0, phone_emb, inW, inln_g, inln_b, ws);
  for (int ly = 0; ly < 3; ++ly) {
    k3p_conv_out<<<BB*LL/64, 256, 0, stream>>>(ws, s4_outb, Dc, ly,
                                               (ly == 2) ? 1 : 0, (ly < 2) ? 1 : 0);
  }
  k5b_pool<<<BB*16, 256, 0, stream>>>(ws);
  k5c_cond<<<BB, 256, 0, stream>>>(ws, gpW, gpb, genW_s, genb_s, genW_sh, genb_sh);
  k5d_fold<<<56, 256, 0, stream>>>(ws, genW_h, genb_h);
  k6_heads<<<BB*LL/64, 512, 0, stream>>>(ws, genb_o, out);
}

// Round 8
// 618.389 us; speedup vs baseline: 1.2055x; 1.0180x over previous
//
#include <hip/hip_runtime.h>
#include <math.h>

// ---------------- problem constants ----------------
#define BB 8
#define LL 8192
#define DD 128
#define NCH 8
#define NST 64
#define TAPS 32          // e^{-0.5*32} ~ 1e-7 relative: FIR truncation far below threshold
#define NOUTD 375
#define NSEG 64          // pool segments per batch (128 tokens each)

// ---------------- MFMA types ----------------
typedef __attribute__((ext_vector_type(8))) short bf16x8;
typedef __attribute__((ext_vector_type(4))) float f32x4;
#define MFMA16(a,b,c) __builtin_amdgcn_mfma_f32_16x16x32_bf16((a),(b),(c),0,0,0)

struct __align__(8) us4 { unsigned short x,y,z,w; };

__device__ __forceinline__ unsigned short f2b(float f) {   // fp32 -> bf16 RNE
  unsigned x = __float_as_uint(f);
  unsigned r = (x + 0x7fffu + ((x >> 16) & 1u)) >> 16;
  return (unsigned short)r;
}
__device__ __forceinline__ float b2f(unsigned short u) {
  return __uint_as_float(((unsigned)u) << 16);
}
__device__ __forceinline__ float silu_f(float x){ return x / (1.f + expf(-x)); }

// ---------------- workspace layout (float offsets) ----------------
static constexpr size_t WS_H      = 0;                             // [B,L,128] fp32 residual
static constexpr size_t WS_LOGITS = WS_H      + (size_t)BB*LL*DD;  // [B,L]
static constexpr size_t WS_SEGM   = WS_LOGITS + (size_t)BB*LL;     // [B,NSEG]
static constexpr size_t WS_SEGS   = WS_SEGM   + BB*NSEG;           // [B,NSEG]
static constexpr size_t WS_SEGV   = WS_SEGS   + BB*NSEG;           // [B,NSEG,128]
static constexpr size_t WS_SCALE  = WS_SEGV   + (size_t)BB*NSEG*DD; // [7,B,128]
static constexpr size_t WS_SHIFT  = WS_SCALE  + (size_t)7*BB*DD;   // [7,B,128]
static constexpr size_t WS_C1     = WS_SHIFT  + (size_t)7*BB*DD;   // [3,128]
static constexpr size_t WS_C2     = WS_C1     + 3*DD;              // [3,128]
static constexpr size_t WS_KTAB   = WS_C2     + 3*DD;              // [3,8,32]
static constexpr size_t WS_GAW    = WS_KTAB   + 3*NCH*TAPS;        // [128]
static constexpr size_t WS_ASCAL  = WS_GAW    + DD;                // 2 (+pad)
static constexpr size_t WS_BASE   = WS_ASCAL  + 32;                // [B,128]
static constexpr size_t WS_BIAS1  = WS_BASE   + BB*DD;             // [B,448] folded gen bias
// ----- ushort (bf16) regions, float-offset based -----
static constexpr size_t WS_ZB_F   = WS_BIAS1  + (size_t)BB*448;    // [B,L,128] bf16 z
static constexpr size_t WS_WGT_F  = WS_ZB_F   + (size_t)BB*LL*DD/2; // [3,128n,128k] bf16 ln-folded inW^T
static constexpr size_t WS_WOT_F  = WS_WGT_F  + (size_t)3*DD*DD/2;  // [3,128n,128k] bf16 outW^T
static constexpr size_t WS_WO2T_F = WS_WOT_F  + (size_t)3*DD*DD/2;  // [7,192n,64k] bf16 genW_o^T
static constexpr size_t WS_WCT_F  = WS_WO2T_F + (size_t)7*192*64/2; // [B,448n,128k] bf16 folded gen W
static constexpr size_t WS_TOTAL  = WS_WCT_F  + (size_t)BB*448*DD/2; // ~13.1M floats = 52.5 MB

__device__ __constant__ int c_offs_d[7] = {0, 1, 2, 102, 294, 358, 370};
__device__ __constant__ int c_dims_d[7] = {1, 1, 100, 192, 64, 12, 5};
// 27 n-tiles of GEMM2 (block-diagonal): (head, local col tile)
__device__ __constant__ int t_hd[27] = {0,1,2,2,2,2,2,2,2,3,3,3,3,3,3,3,3,3,3,3,3,4,4,4,4,5,6};
__device__ __constant__ int t_nl[27] = {0,0,0,1,2,3,4,5,6,0,1,2,3,4,5,6,7,8,9,10,11,0,1,2,3,0,0};

// ================= K0: fold weights, tabulate FIR taps, bf16 weight transposes (35 blocks) =====
// blk 0-2: per-layer wgt/wot/C1/C2; blk 3-26: taps (ly,cx); blk 27: BASE+GAW+ASCAL; blk 28-34: wo2t
__global__ __launch_bounds__(256) void k0_setup(
    const float* s4_ln_g, const float* s4_ln_b, const float* s4_inW, const float* s4_inb,
    const float* s4_outW,
    const float* lam_re, const float* lam_im, const float* Bn, const float* Cre, const float* Cim,
    const float* attn_g, const float* attn_lnb, const float* attn_w, const float* attn_bias,
    const int* singer_id, const int* language_id,
    const float* singer_emb, const float* lang_emb, const float* inW, const float* inb,
    const float* genW_o, float* ws)
{
  int blk = blockIdx.x, tid = threadIdx.x;
  if (blk < 3) {
    __shared__ __align__(16) unsigned short tile[128*136];
    __shared__ float c1p[256], c2p[256];
    int ly = blk;
    int n = tid & 127;
    float c1a = 0.f, c2a = 0.f;
    for (int j = 0; j < 64; ++j) {
      int k = (tid >> 7) + 2*j;
      float v  = s4_inW[((size_t)ly*DD + k)*DD + n];       // coalesced
      float gk = s4_ln_g[ly*DD + k];
      float bk = s4_ln_b[ly*DD + k];
      tile[k*136 + n] = f2b(gk*v);
      c1a += gk*v; c2a += bk*v;
    }
    c1p[tid] = c1a; c2p[tid] = c2a;
    __syncthreads();
    if (tid < DD) {
      ws[WS_C1 + ly*DD + tid] = c1p[tid] + c1p[tid+128];
      ws[WS_C2 + ly*DD + tid] = c2p[tid] + c2p[tid+128] + s4_inb[ly*DD + tid];
    }
    unsigned short* wgt = (unsigned short*)(ws + WS_WGT_F);
    for (int o = tid; o < DD*DD; o += 256) {
      int nn = o >> 7, k = o & 127;
      wgt[ly*DD*DD + o] = tile[k*136 + nn];
    }
    __syncthreads();
    for (int j = 0; j < 64; ++j) {
      int k = (tid >> 7) + 2*j;
      tile[k*136 + n] = f2b(s4_outW[((size_t)ly*DD + k)*DD + n]);
    }
    __syncthreads();
    unsigned short* wot = (unsigned short*)(ws + WS_WOT_F);
    for (int o = tid; o < DD*DD; o += 256) {
      int nn = o >> 7, k = o & 127;
      wot[ly*DD*DD + o] = tile[k*136 + nn];
    }
  } else if (blk < 27) {
    // ---- FIR taps for (ly,cx) -> KTAB ----
    __shared__ float part[256];
    int ly = (blk - 3) >> 3, cx = (blk - 3) & 7;
    int dt = tid & 31, nc = tid >> 5;
    const float* lre = lam_re + (ly*NCH + cx)*NST;
    const float* lim = lam_im + (ly*NCH + cx)*NST;
    const float* bn  = Bn  + (ly*NCH + cx)*NST;
    const float* cre = Cre + (ly*NCH + cx)*NST;
    const float* cim = Cim + (ly*NCH + cx)*NST;
    float td = (float)dt, acc = 0.f;
    for (int nn = nc*8; nn < nc*8 + 8; ++nn) {
      float e = expf(lre[nn]*td);
      float ang = lim[nn]*td;
      acc += bn[nn]*(cre[nn]*cosf(ang) - cim[nn]*sinf(ang))*e;
    }
    part[tid] = acc;
    __syncthreads();
    if (tid < 32) {
      float a = 0.f;
      #pragma unroll
      for (int i = 0; i < 8; ++i) a += part[i*32 + tid];
      ws[WS_KTAB + (ly*NCH + cx)*TAPS + tid] = a;
    }
  } else if (blk == 27) {
    for (int o = tid; o < BB*DD; o += 256) {
      int b = o >> 7, d = o & 127;
      int sid = singer_id[b], lid = language_id[b];
      float acc = inb[d];
      for (int j = 0; j < 32; ++j) acc += singer_emb[sid*32 + j]*inW[(64 + j)*DD + d];
      for (int j = 0; j < 16; ++j) acc += lang_emb[lid*16 + j]*inW[(96 + j)*DD + d];
      ws[WS_BASE + o] = acc;
    }
    if (tid < DD) ws[WS_GAW + tid] = attn_g[tid]*attn_w[tid];
    if (tid == 0) {
      float c1s = 0.f, c2s = 0.f;
      for (int d = 0; d < DD; ++d) { c1s += attn_g[d]*attn_w[d]; c2s += attn_lnb[d]*attn_w[d]; }
      ws[WS_ASCAL+0] = c1s;
      ws[WS_ASCAL+1] = c2s + attn_bias[0];
    }
  } else {
    // ---- wo2t for head hd: [192n][64k] via LDS ----
    __shared__ float gw[64*200];
    int hd = blk - 28;
    for (int k = 0; k < 64; ++k) {
      if (tid < 192) gw[k*200 + tid] = genW_o[((size_t)hd*64 + k)*192 + tid];
    }
    __syncthreads();
    unsigned short* wo2t = (unsigned short*)(ws + WS_WO2T_F);
    for (int o = tid; o < 192*64; o += 256) {
      int nn = o >> 6, k = o & 63;
      wo2t[(size_t)hd*192*64 + o] = f2b(gw[k*200 + nn]);
    }
  }
}

// ================= K1p: embed + input proj + LN + SiLU -> h (fp32) + fused ly0 LN+in_proj -> z0 =====
__global__ __launch_bounds__(256) void k1p_input(
    const int* phone_seq, const float* f0, const float* phone_emb,
    const float* inW, const float* inln_g, const float* inln_b, float* ws)
{
  __shared__ __align__(16) float pm[64*72];
  __shared__ __align__(16) unsigned short hm[64*136];   // bf16 h tile for z0 MFMA
  __shared__ int   ps[64];
  __shared__ float fv[64];
  __shared__ float rs_s[64], mrs_s[64];
  int tid = threadIdx.x;
  size_t gbase = (size_t)blockIdx.x * 64;
  if (tid < 64) { ps[tid] = phone_seq[gbase + tid]; fv[tid] = f0[gbase + tid]; }
  __syncthreads();
  #pragma unroll
  for (int j = 0; j < 4; ++j) {
    int idx4 = tid + 256*j;
    int tok = idx4 >> 4, col = idx4 & 15;
    float4 v = *(const float4*)(phone_emb + (size_t)ps[tok]*64 + col*4);
    *(float4*)(pm + tok*72 + col*4) = v;
  }
  __syncthreads();
  int ti = tid >> 5, di = tid & 31, d0 = di*4;
  float acc[8][4];
  #pragma unroll
  for (int i = 0; i < 8; ++i) { acc[i][0]=0.f; acc[i][1]=0.f; acc[i][2]=0.f; acc[i][3]=0.f; }
  for (int kk = 0; kk < 64; kk += 4) {
    float4 w0 = *(const float4*)(inW + (kk+0)*DD + d0);
    float4 w1 = *(const float4*)(inW + (kk+1)*DD + d0);
    float4 w2 = *(const float4*)(inW + (kk+2)*DD + d0);
    float4 w3 = *(const float4*)(inW + (kk+3)*DD + d0);
    #pragma unroll
    for (int i = 0; i < 8; ++i) {
      float4 a = *(float4*)(pm + (ti*8 + i)*72 + kk);
      acc[i][0] += a.x*w0.x + a.y*w1.x + a.z*w2.x + a.w*w3.x;
      acc[i][1] += a.x*w0.y + a.y*w1.y + a.z*w2.y + a.w*w3.y;
      acc[i][2] += a.x*w0.z + a.y*w1.z + a.z*w2.z + a.w*w3.z;
      acc[i][3] += a.x*w0.w + a.y*w1.w + a.z*w2.w + a.w*w3.w;
    }
  }
  float4 w112 = *(const float4*)(inW + 112*DD + d0);
  int b = (int)(gbase >> 13);
  float4 bs  = *(const float4*)(ws + WS_BASE + b*DD + d0);
  float4 lg4 = *(const float4*)(inln_g + d0);
  float4 lb4 = *(const float4*)(inln_b + d0);
  float s2[8], ss2[8];
  #pragma unroll
  for (int i = 0; i < 8; ++i) {
    int tok = ti*8 + i;
    float fz = fv[tok];
    float y0 = acc[i][0] + fz*w112.x + bs.x;
    float y1 = acc[i][1] + fz*w112.y + bs.y;
    float y2 = acc[i][2] + fz*w112.z + bs.z;
    float y3 = acc[i][3] + fz*w112.w + bs.w;
    float s  = y0+y1+y2+y3;
    float ss = y0*y0+y1*y1+y2*y2+y3*y3;
    #pragma unroll
    for (int m = 16; m >= 1; m >>= 1) { s += __shfl_xor(s, m); ss += __shfl_xor(ss, m); }
    float mean = s * 0.0078125f;
    float var  = ss * 0.0078125f - mean*mean;
    float rstd = rsqrtf(var + 1e-5f);
    y0 = silu_f((y0 - mean)*rstd*lg4.x + lb4.x);
    y1 = silu_f((y1 - mean)*rstd*lg4.y + lb4.y);
    y2 = silu_f((y2 - mean)*rstd*lg4.z + lb4.z);
    y3 = silu_f((y3 - mean)*rstd*lg4.w + lb4.w);
    *(float4*)(ws + WS_H + (gbase + tok)*DD + d0) = make_float4(y0,y1,y2,y3);
    us4 p; p.x = f2b(y0); p.y = f2b(y1); p.z = f2b(y2); p.w = f2b(y3);
    *(us4*)(hm + tok*136 + d0) = p;
    s2[i]  = y0+y1+y2+y3;
    ss2[i] = y0*y0+y1*y1+y2*y2+y3*y3;
  }
  #pragma unroll
  for (int m = 16; m >= 1; m >>= 1) {
    #pragma unroll
    for (int i = 0; i < 8; ++i) { s2[i] += __shfl_xor(s2[i], m); ss2[i] += __shfl_xor(ss2[i], m); }
  }
  if (di == 0) {
    #pragma unroll
    for (int i = 0; i < 8; ++i) {
      int tok = ti*8 + i;
      float mean = s2[i]*0.0078125f;
      float var  = ss2[i]*0.0078125f - mean*mean;
      float rstd = rsqrtf(var + 1e-5f);
      rs_s[tok] = rstd; mrs_s[tok] = mean*rstd;
    }
  }
  __syncthreads();
  // ---- z0 = folded-LN(h0) @ Wg0 via MFMA ----
  int w = tid >> 6, lane = tid & 63, q = lane >> 4, c = lane & 15;
  int m16 = w*16;
  const unsigned short* wgt = (const unsigned short*)(ws + WS_WGT_F);  // ly 0
  bf16x8 aF[4];
  #pragma unroll
  for (int kk = 0; kk < 4; ++kk)
    aF[kk] = *(const bf16x8*)(hm + (m16 + c)*136 + kk*32 + q*8);
  float rsv[4], mrv[4];
  #pragma unroll
  for (int r = 0; r < 4; ++r) { int row = m16 + q*4 + r; rsv[r] = rs_s[row]; mrv[r] = mrs_s[row]; }
  unsigned short* zb = (unsigned short*)(ws + WS_ZB_F);
  #pragma unroll
  for (int nt = 0; nt < 8; ++nt) {
    f32x4 za = {0.f,0.f,0.f,0.f};
    #pragma unroll
    for (int kk = 0; kk < 4; ++kk) {
      bf16x8 bF = *(const bf16x8*)(wgt + (nt*16 + c)*DD + kk*32 + q*8);
      za = MFMA16(aF[kk], bF, za);
    }
    int col = nt*16 + c;
    float c1v = ws[WS_C1 + col];
    float c2v = ws[WS_C2 + col];
    #pragma unroll
    for (int r = 0; r < 4; ++r) {
      float zv = rsv[r]*za[r] - mrv[r]*c1v + c2v;
      zb[(gbase + m16 + q*4 + r)*DD + col] = f2b(zv);
    }
  }
}

// ===== K3p: FIR conv + skip + MFMA out_proj + SiLU + residual (+logits) + fused next-layer LN+in_proj
__global__ __launch_bounds__(256) void k3p_conv_out(
    float* ws, const float* s4_outb, const float* Dc, int ly, int do_logits, int do_z)
{
  __shared__ __align__(16) unsigned short zw[128*128];  // conv window; reused as hn bf16 tile after conv
  __shared__ __align__(16) unsigned short ym[64*136];   // bf16 A-tile for out_proj
  __shared__ float k2t[8*64];
  __shared__ float dcs[8];
  __shared__ float rs2[64], mrs2[64];
  int tid = threadIdx.x, blk = blockIdx.x;
  int b  = blk >> 7;
  int t0 = (blk & 127) * 64;
  const unsigned short* zbp = (const unsigned short*)(ws + WS_ZB_F);
  #pragma unroll
  for (int j = 0; j < 8; ++j) {
    int idx8 = tid + 256*j;            // 128 tok x 16 ushort8
    int tok = idx8 >> 4, c8 = idx8 & 15;
    int t = t0 - 32 + tok;
    bf16x8 v = {0,0,0,0,0,0,0,0};
    if (t >= 0 && t < LL) v = *(const bf16x8*)(zbp + ((size_t)b*LL + t)*DD + c8*8);
    *(bf16x8*)(zw + tok*DD + c8*8) = v;
  }
  for (int o = tid; o < 512; o += 256) {     // K2[j]: j=-31..32 -> m=0..63
    int c = o >> 6, m = o & 63;
    int idx = (m <= 31) ? (31 - m) : (m - 32);
    k2t[o] = ws[WS_KTAB + (ly*NCH + c)*TAPS + idx];
  }
  if (tid < 8) dcs[tid] = Dc[ly*NCH + tid];
  __syncthreads();
  // conv: 2 passes, thread = (token half16, channel)
  #pragma unroll
  for (int p = 0; p < 2; ++p) {
    int half = p*2 + (tid >> 7), ch = tid & 127, cx = ch >> 4;
    int base = 1 + half*16;
    float ring[16], accv[16];
    #pragma unroll
    for (int x = 0; x < 16; ++x) { ring[x] = b2f(zw[(base + x)*DD + ch]); accv[x] = 0.f; }
    #pragma unroll
    for (int m = 0; m < 64; ++m) {
      float kf = k2t[cx*64 + m];
      #pragma unroll
      for (int i = 0; i < 16; ++i) accv[i] += kf * ring[(m + i) & 15];
      if (m < 63) ring[m & 15] = b2f(zw[(base + m + 16)*DD + ch]);
    }
    float dcv = dcs[cx];
    #pragma unroll
    for (int i = 0; i < 16; ++i) {
      int tl = half*16 + i;
      ym[tl*136 + ch] = f2b(accv[i] + dcv * b2f(zw[(32 + tl)*DD + ch]));
    }
  }
  __syncthreads();
  // MFMA out_proj: wave w -> rows w*16..+15. After this sync zw is dead -> reuse as hn bf16 tile.
  unsigned short* hm2 = zw;   // [64][136] bf16 hn tile
  int w = tid >> 6, lane = tid & 63, q = lane >> 4, c = lane & 15;
  int m16 = w*16;
  const unsigned short* wot = (const unsigned short*)(ws + WS_WOT_F) + ly*DD*DD;
  bf16x8 aF[4];
  #pragma unroll
  for (int kk = 0; kk < 4; ++kk)
    aF[kk] = *(const bf16x8*)(ym + (m16 + c)*136 + kk*32 + q*8);
  float* hbuf = ws + WS_H;
  float c1s = ws[WS_ASCAL+0], c2s = ws[WS_ASCAL+1];
  float sr[4] = {0,0,0,0}, ssr[4] = {0,0,0,0}, dtr[4] = {0,0,0,0};
  #pragma unroll
  for (int nt = 0; nt < 8; ++nt) {
    f32x4 acc = {0.f,0.f,0.f,0.f};
    #pragma unroll
    for (int kk = 0; kk < 4; ++kk) {
      bf16x8 bF = *(const bf16x8*)(wot + (nt*16 + c)*DD + kk*32 + q*8);
      acc = MFMA16(aF[kk], bF, acc);
    }
    int col = nt*16 + c;
    float ob = s4_outb[ly*DD + col];
    float gw = ws[WS_GAW + col];
    #pragma unroll
    for (int r = 0; r < 4; ++r) {
      size_t gofs = ((size_t)b*LL + t0 + m16 + q*4 + r)*DD + col;
      float hold = hbuf[gofs];
      float hn = hold + silu_f(acc[r] + ob);
      hbuf[gofs] = hn;
      hm2[(m16 + q*4 + r)*136 + col] = f2b(hn);
      sr[r] += hn; ssr[r] += hn*hn;
      if (do_logits) dtr[r] += hn*gw;
    }
  }
  #pragma unroll
  for (int m = 8; m >= 1; m >>= 1) {
    #pragma unroll
    for (int r = 0; r < 4; ++r) {
      sr[r]  += __shfl_xor(sr[r],  m);
      ssr[r] += __shfl_xor(ssr[r], m);
      if (do_logits) dtr[r] += __shfl_xor(dtr[r], m);
    }
  }
  if (c < 4) {
    int r = c;
    float mean = sr[r]*0.0078125f;
    float var  = ssr[r]*0.0078125f - mean*mean;
    float rstd = rsqrtf(var + 1e-5f);
    int row = m16 + q*4 + r;
    if (do_z) { rs2[row] = rstd; mrs2[row] = mean*rstd; }
    if (do_logits)
      ws[WS_LOGITS + (size_t)b*LL + t0 + row] = rstd*dtr[r] - mean*rstd*c1s + c2s;
  }
  if (do_z) {
    __syncthreads();
    const unsigned short* wgt2 = (const unsigned short*)(ws + WS_WGT_F) + (ly+1)*DD*DD;
    bf16x8 aF2[4];
    #pragma unroll
    for (int kk = 0; kk < 4; ++kk)
      aF2[kk] = *(const bf16x8*)(hm2 + (m16 + c)*136 + kk*32 + q*8);
    float rsv[4], mrv[4];
    #pragma unroll
    for (int r = 0; r < 4; ++r) { int row = m16 + q*4 + r; rsv[r] = rs2[row]; mrv[r] = mrs2[row]; }
    unsigned short* zb = (unsigned short*)(ws + WS_ZB_F);
    size_t gbase = (size_t)b*LL + t0;
    #pragma unroll
    for (int nt = 0; nt < 8; ++nt) {
      f32x4 za = {0.f,0.f,0.f,0.f};
      #pragma unroll
      for (int kk = 0; kk < 4; ++kk) {
        bf16x8 bF = *(const bf16x8*)(wgt2 + (nt*16 + c)*DD + kk*32 + q*8);
        za = MFMA16(aF2[kk], bF, za);
      }
      int col = nt*16 + c;
      float c1v = ws[WS_C1 + (ly+1)*DD + col];
      float c2v = ws[WS_C2 + (ly+1)*DD + col];
      #pragma unroll
      for (int r = 0; r < 4; ++r) {
        float zv = rsv[r]*za[r] - mrv[r]*c1v + c2v;
        zb[(gbase + m16 + q*4 + r)*DD + col] = f2b(zv);
      }
    }
  }
}

// ================= K5b: segmented softmax + weighted pool partials (NSEG=64 x 128 tokens) =====
__global__ __launch_bounds__(256) void k5b_pool(float* ws)
{
  int blk = blockIdx.x, tid = threadIdx.x;
  int b = blk >> 6, seg = blk & 63;
  const float* lg = ws + WS_LOGITS + (size_t)b*LL + seg*128;
  __shared__ float ev[128];
  __shared__ float red[4], red2[4];
  __shared__ float vr[2][128];
  float a0 = (tid < 128) ? lg[tid] : -1e30f;
  float mx = a0;
  #pragma unroll
  for (int m = 32; m >= 1; m >>= 1) mx = fmaxf(mx, __shfl_xor(mx, m));
  if ((tid & 63) == 0) red[tid >> 6] = mx;
  __syncthreads();
  float M = fmaxf(fmaxf(red[0], red[1]), fmaxf(red[2], red[3]));
  float e0 = (tid < 128) ? expf(a0 - M) : 0.f;
  if (tid < 128) ev[tid] = e0;
  float s = e0;
  #pragma unroll
  for (int m = 32; m >= 1; m >>= 1) s += __shfl_xor(s, m);
  if ((tid & 63) == 0) red2[tid >> 6] = s;
  __syncthreads();
  float S = red2[0] + red2[1] + red2[2] + red2[3];
  int ls = tid >> 7, d = tid & 127;
  const float* hb = ws + WS_H + ((size_t)b*LL + seg*128)*DD;
  float acc = 0.f;
  for (int jj = 0; jj < 64; ++jj) {
    int tok = jj*2 + ls;
    acc += ev[tok] * hb[(size_t)tok*DD + d];
  }
  vr[ls][d] = acc;
  __syncthreads();
  if (tid < 128) ws[WS_SEGV + (size_t)(b*NSEG + seg)*DD + tid] = vr[0][tid] + vr[1][tid];
  if (tid == 0) { ws[WS_SEGM + b*NSEG + seg] = M; ws[WS_SEGS + b*NSEG + seg] = S; }
}

// ================= K5c: combine pool, g, FiLM scale/shift (grid 8, per batch) =================
__global__ __launch_bounds__(256) void k5c_cond(
    float* ws, const float* gpW, const float* gpb,
    const float* genW_s, const float* genb_s, const float* genW_sh, const float* genb_sh)
{
  __shared__ float wsg[NSEG];
  __shared__ float Ssh[1];
  __shared__ float gpre[DD];
  __shared__ float red[256];
  __shared__ float gg[32];
  int b = blockIdx.x, tid = threadIdx.x;
  if (tid == 0) {
    float M = -1e30f;
    for (int sg = 0; sg < NSEG; ++sg) M = fmaxf(M, ws[WS_SEGM + b*NSEG + sg]);
    float S = 0.f;
    for (int sg = 0; sg < NSEG; ++sg) {
      float e = expf(ws[WS_SEGM + b*NSEG + sg] - M);
      wsg[sg] = e;
      S += ws[WS_SEGS + b*NSEG + sg]*e;
    }
    Ssh[0] = S;
  }
  __syncthreads();
  if (tid < DD) {
    float V = 0.f;
    for (int sg = 0; sg < NSEG; ++sg)
      V += ws[WS_SEGV + (size_t)(b*NSEG + sg)*DD + tid]*wsg[sg];
    gpre[tid] = V / Ssh[0];
  }
  __syncthreads();
  {
    int c = tid & 31, kc = tid >> 5;   // 8 chunks x 16 k
    float p = 0.f;
    for (int k = kc*16; k < kc*16 + 16; ++k) p += gpre[k]*gpW[k*32 + c];
    red[tid] = p;
  }
  __syncthreads();
  if (tid < 32) {
    float a = gpb[tid];
    #pragma unroll
    for (int i = 0; i < 8; ++i) a += red[i*32 + tid];
    gg[tid] = a;
  }
  __syncthreads();
  for (int o = tid; o < 7*DD; o += 256) {
    int hd = o >> 7, d = o & 127;
    float sc = genb_s[hd*DD + d], sh = genb_sh[hd*DD + d];
    for (int c = 0; c < 32; ++c) {
      float g = gg[c];
      sc += g*genW_s[((size_t)hd*32 + c)*DD + d];
      sh += g*genW_sh[((size_t)hd*32 + c)*DD + d];
    }
    ws[WS_SCALE + (size_t)hd*BB*DD + b*DD + d] = sc;
    ws[WS_SHIFT + (size_t)hd*BB*DD + b*DD + d] = sh;
  }
}

// ================= K5d: build folded generator weights Wcat (bf16) + bias1 (grid 7, per head) =====
__global__ __launch_bounds__(256) void k5d_fold(float* ws, const float* genW_h, const float* genb_h)
{
  __shared__ float wh[128*65];   // [k][j], pad 65
  __shared__ float red[256];
  int hd = blockIdx.x, tid = threadIdx.x;
  for (int o = tid; o < DD*64; o += 256) {
    int k = o >> 6, j = o & 63;
    wh[k*65 + j] = genW_h[(size_t)hd*DD*64 + o];   // coalesced
  }
  __syncthreads();
  unsigned short* wct = (unsigned short*)(ws + WS_WCT_F);
  for (int b = 0; b < BB; ++b) {
    const float* sc = ws + WS_SCALE + (size_t)hd*BB*DD + b*DD;
    const float* sh = ws + WS_SHIFT + (size_t)hd*BB*DD + b*DD;
    for (int o = tid; o < 64*DD; o += 256) {
      int j = o >> 7, k = o & 127;
      wct[((size_t)b*448 + hd*64 + j)*DD + k] = f2b(sc[k]*wh[k*65 + j]);
    }
    {
      int j = tid >> 2, kc = tid & 3;   // 64 j x 4 chunks of 32 k
      float p = 0.f;
      for (int k = kc*32; k < kc*32 + 32; ++k) p += sh[k]*wh[k*65 + j];
      red[tid] = p;
      __syncthreads();
      if (tid < 64)
        ws[WS_BIAS1 + b*448 + hd*64 + tid] =
          genb_h[hd*64 + tid] + red[tid*4] + red[tid*4+1] + red[tid*4+2] + red[tid*4+3];
      __syncthreads();
    }
  }
}

// ================= K6: generator heads, M=64 tiles, 512 threads; launched as 2 half-grids =====
__global__ __launch_bounds__(512) void k6_heads(float* ws, const float* genb_o, float* out, int blk0)
{
  __shared__ __align__(16) unsigned short hm[64*136];   // bf16 h tile
  __shared__ __align__(16) unsigned short rm[64*456];   // bf16 r tile (448 + pad)
  int tid = threadIdx.x, blk = blockIdx.x + blk0;
  int b = blk >> 7, t0 = (blk & 127)*64;
  const float* hb = ws + WS_H + ((size_t)b*LL + t0)*DD;
  #pragma unroll
  for (int j = 0; j < 4; ++j) {
    int idx4 = tid + 512*j;                 // 64 tok x 32 float4
    int tok = idx4 >> 5, c4 = idx4 & 31;
    float4 v = *(const float4*)(hb + (size_t)idx4*4);
    us4 p; p.x = f2b(v.x); p.y = f2b(v.y); p.z = f2b(v.z); p.w = f2b(v.w);
    *(us4*)(hm + tok*136 + c4*4) = p;
  }
  __syncthreads();
  int w = tid >> 6, lane = tid & 63, q = lane >> 4, c = lane & 15;
  int mi = w & 3, nh = w >> 2;
  int m16 = mi*16;
  {
    bf16x8 aF[4];
    #pragma unroll
    for (int kk = 0; kk < 4; ++kk)
      aF[kk] = *(const bf16x8*)(hm + (m16 + c)*136 + kk*32 + q*8);
    const unsigned short* wct = (const unsigned short*)(ws + WS_WCT_F) + (size_t)b*448*DD;
    #pragma unroll 2
    for (int ntl = 0; ntl < 14; ++ntl) {
      int nt = nh*14 + ntl;
      f32x4 acc = {0.f,0.f,0.f,0.f};
      #pragma unroll
      for (int kk = 0; kk < 4; ++kk) {
        bf16x8 bF = *(const bf16x8*)(wct + ((size_t)nt*16 + c)*DD + kk*32 + q*8);
        acc = MFMA16(aF[kk], bF, acc);
      }
      int col = nt*16 + c;
      float bias = ws[WS_BIAS1 + b*448 + col];
      #pragma unroll
      for (int r = 0; r < 4; ++r)
        rm[(m16 + q*4 + r)*456 + col] = f2b(silu_f(acc[r] + bias));
    }
  }
  __syncthreads();
  {
    const unsigned short* wo2t = (const unsigned short*)(ws + WS_WO2T_F);
    int i0 = (nh == 0) ? 0 : 14;
    int i1 = (nh == 0) ? 14 : 27;
    #pragma unroll 2
    for (int i = i0; i < i1; ++i) {
      int hd = t_hd[i], nl = t_nl[i];
      bf16x8 aF0 = *(const bf16x8*)(rm + (m16 + c)*456 + hd*64 + q*8);
      bf16x8 aF1 = *(const bf16x8*)(rm + (m16 + c)*456 + hd*64 + 32 + q*8);
      f32x4 acc = {0.f,0.f,0.f,0.f};
      bf16x8 bF0 = *(const bf16x8*)(wo2t + ((size_t)hd*192 + nl*16 + c)*64 + q*8);
      bf16x8 bF1 = *(const bf16x8*)(wo2t + ((size_t)hd*192 + nl*16 + c)*64 + 32 + q*8);
      acc = MFMA16(aF0, bF0, acc);
      acc = MFMA16(aF1, bF1, acc);
      int cl = nl*16 + c;
      int di = c_dims_d[hd];
      if (cl < di) {
        float bo = genb_o[hd*192 + cl];
        #pragma unroll
        for (int r = 0; r < 4; ++r)
          out[((size_t)b*LL + t0 + m16 + q*4 + r)*NOUTD + c_offs_d[hd] + cl] = acc[r] + bo;
      }
    }
  }
}

// ================= launch =================
extern "C" void kernel_launch(void* const* d_in, const int* in_sizes, int n_in,
                              void* d_out, int out_size, void* d_ws, size_t ws_size,
                              hipStream_t stream) {
  const int*   phone_seq   = (const int*)  d_in[0];
  const int*   singer_id   = (const int*)  d_in[1];
  const int*   language_id = (const int*)  d_in[2];
  const float* f0          = (const float*)d_in[3];
  const float* phone_emb   = (const float*)d_in[4];
  const float* singer_emb  = (const float*)d_in[5];
  const float* lang_emb    = (const float*)d_in[6];
  const float* inW         = (const float*)d_in[7];
  const float* inb         = (const float*)d_in[8];
  const float* inln_g      = (const float*)d_in[9];
  const float* inln_b      = (const float*)d_in[10];
  const float* s4_ln_g     = (const float*)d_in[11];
  const float* s4_ln_b     = (const float*)d_in[12];
  const float* s4_inW      = (const float*)d_in[13];
  const float* s4_inb      = (const float*)d_in[14];
  const float* s4_outW     = (const float*)d_in[15];
  const float* s4_outb     = (const float*)d_in[16];
  const float* lam_re      = (const float*)d_in[17];
  const float* lam_im      = (const float*)d_in[18];
  const float* Bn          = (const float*)d_in[19];
  const float* C_re        = (const float*)d_in[20];
  const float* C_im        = (const float*)d_in[21];
  const float* Dc          = (const float*)d_in[22];
  const float* attn_g      = (const float*)d_in[23];
  const float* attn_lnb    = (const float*)d_in[24];
  const float* attn_w      = (const float*)d_in[25];
  const float* attn_bias   = (const float*)d_in[26];
  const float* gpW         = (const float*)d_in[27];
  const float* gpb         = (const float*)d_in[28];
  const float* genW_s      = (const float*)d_in[29];
  const float* genb_s      = (const float*)d_in[30];
  const float* genW_sh     = (const float*)d_in[31];
  const float* genb_sh     = (const float*)d_in[32];
  const float* genW_h      = (const float*)d_in[33];
  const float* genb_h      = (const float*)d_in[34];
  const float* genW_o      = (const float*)d_in[35];
  const float* genb_o      = (const float*)d_in[36];
  float* ws  = (float*)d_ws;
  float* out = (float*)d_out;

  k0_setup<<<35, 256, 0, stream>>>(s4_ln_g, s4_ln_b, s4_inW, s4_inb, s4_outW,
                                   lam_re, lam_im, Bn, C_re, C_im,
                                   attn_g, attn_lnb, attn_w, attn_bias,
                                   singer_id, language_id, singer_emb, lang_emb, inW, inb,
                                   genW_o, ws);
  k1p_input<<<BB*LL/64, 256, 0, stream>>>(phone_seq, f0, phone_emb, inW, inln_g, inln_b, ws);
  for (int ly = 0; ly < 3; ++ly) {
    k3p_conv_out<<<BB*LL/64, 256, 0, stream>>>(ws, s4_outb, Dc, ly,
                                               (ly == 2) ? 1 : 0, (ly < 2) ? 1 : 0);
  }
  k5b_pool<<<BB*NSEG, 256, 0, stream>>>(ws);
  k5c_cond<<<BB, 256, 0, stream>>>(ws, gpW, gpb, genW_s, genb_s, genW_sh, genb_sh);
  k5d_fold<<<7, 256, 0, stream>>>(ws, genW_h, genb_h);
  k6_heads<<<512, 512, 0, stream>>>(ws, genb_o, out, 0);
  k6_heads<<<512, 512, 0, stream>>>(ws, genb_o, out, 512);
}

// Round 10
// 514.298 us; speedup vs baseline: 1.4494x; 1.2024x over previous
//
#include <hip/hip_runtime.h>
#include <math.h>

// ---------------- problem constants ----------------
#define BB 8
#define LL 8192
#define DD 128
#define NCH 8
#define NST 64
#define TAPS 32          // e^{-0.5*32} ~ 1e-7 relative: FIR truncation far below threshold
#define NOUTD 375
#define NSEG 64          // pool segments per batch (128 tokens each)

// ---------------- MFMA types ----------------
typedef __attribute__((ext_vector_type(8))) short bf16x8;
typedef __attribute__((ext_vector_type(4))) float f32x4;
#define MFMA16(a,b,c) __builtin_amdgcn_mfma_f32_16x16x32_bf16((a),(b),(c),0,0,0)

struct __align__(8) us4 { unsigned short x,y,z,w; };

__device__ __forceinline__ unsigned short f2b(float f) {   // fp32 -> bf16 RNE
  unsigned x = __float_as_uint(f);
  unsigned r = (x + 0x7fffu + ((x >> 16) & 1u)) >> 16;
  return (unsigned short)r;
}
__device__ __forceinline__ float b2f(unsigned short u) {
  return __uint_as_float(((unsigned)u) << 16);
}
__device__ __forceinline__ float silu_f(float x){ return x / (1.f + expf(-x)); }

// ---------------- workspace layout (float offsets) ----------------
static constexpr size_t WS_H      = 0;                             // [B,L,128] fp32 residual
static constexpr size_t WS_LOGITS = WS_H      + (size_t)BB*LL*DD;  // [B,L]
static constexpr size_t WS_SEGM   = WS_LOGITS + (size_t)BB*LL;     // [B,NSEG]
static constexpr size_t WS_SEGS   = WS_SEGM   + BB*NSEG;           // [B,NSEG]
static constexpr size_t WS_SEGV   = WS_SEGS   + BB*NSEG;           // [B,NSEG,128]
static constexpr size_t WS_SCALE  = WS_SEGV   + (size_t)BB*NSEG*DD; // repurposed: gg[B,32]
static constexpr size_t WS_SHIFT  = WS_SCALE  + (size_t)7*BB*DD;   // (unused)
static constexpr size_t WS_C1     = WS_SHIFT  + (size_t)7*BB*DD;   // [3,128]
static constexpr size_t WS_C2     = WS_C1     + 3*DD;              // [3,128]
static constexpr size_t WS_KTAB   = WS_C2     + 3*DD;              // [3,8,32]
static constexpr size_t WS_GAW    = WS_KTAB   + 3*NCH*TAPS;        // [128]
static constexpr size_t WS_ASCAL  = WS_GAW    + DD;                // 2 (+pad)
static constexpr size_t WS_BASE   = WS_ASCAL  + 32;                // [B,128]
static constexpr size_t WS_BIAS1  = WS_BASE   + BB*DD;             // [B,448] folded gen bias
// ----- ushort (bf16) regions, float-offset based -----
static constexpr size_t WS_ZB_F   = WS_BIAS1  + (size_t)BB*448;    // [B,L,128] bf16 z
static constexpr size_t WS_WGT_F  = WS_ZB_F   + (size_t)BB*LL*DD/2; // [3,128n,128k] bf16 ln-folded inW^T
static constexpr size_t WS_WOT_F  = WS_WGT_F  + (size_t)3*DD*DD/2;  // [3,128n,128k] bf16 outW^T
static constexpr size_t WS_WO2T_F = WS_WOT_F  + (size_t)3*DD*DD/2;  // [7,192n,64k] bf16 genW_o^T
static constexpr size_t WS_WCT_F  = WS_WO2T_F + (size_t)7*192*64/2; // [B,448n,128k] bf16 folded gen W
static constexpr size_t WS_TOTAL  = WS_WCT_F  + (size_t)BB*448*DD/2; // ~13.1M floats = 52.5 MB

__device__ __constant__ int c_offs_d[7] = {0, 1, 2, 102, 294, 358, 370};
__device__ __constant__ int c_dims_d[7] = {1, 1, 100, 192, 64, 12, 5};
// 27 n-tiles of GEMM2 (block-diagonal): (head, local col tile)
__device__ __constant__ int t_hd[27] = {0,1,2,2,2,2,2,2,2,3,3,3,3,3,3,3,3,3,3,3,3,4,4,4,4,5,6};
__device__ __constant__ int t_nl[27] = {0,0,0,1,2,3,4,5,6,0,1,2,3,4,5,6,7,8,9,10,11,0,1,2,3,0,0};

// ================= K0: fold weights, tabulate FIR taps, bf16 weight transposes (35 blocks) =====
// blk 0-2: per-layer wgt/wot/C1/C2; blk 3-26: taps (ly,cx); blk 27: BASE+GAW+ASCAL; blk 28-34: wo2t
__global__ __launch_bounds__(256) void k0_setup(
    const float* s4_ln_g, const float* s4_ln_b, const float* s4_inW, const float* s4_inb,
    const float* s4_outW,
    const float* lam_re, const float* lam_im, const float* Bn, const float* Cre, const float* Cim,
    const float* attn_g, const float* attn_lnb, const float* attn_w, const float* attn_bias,
    const int* singer_id, const int* language_id,
    const float* singer_emb, const float* lang_emb, const float* inW, const float* inb,
    const float* genW_o, float* ws)
{
  int blk = blockIdx.x, tid = threadIdx.x;
  if (blk < 3) {
    __shared__ __align__(16) unsigned short tile[128*136];
    __shared__ float c1p[256], c2p[256];
    int ly = blk;
    int n = tid & 127;
    float c1a = 0.f, c2a = 0.f;
    for (int j = 0; j < 64; ++j) {
      int k = (tid >> 7) + 2*j;
      float v  = s4_inW[((size_t)ly*DD + k)*DD + n];       // coalesced
      float gk = s4_ln_g[ly*DD + k];
      float bk = s4_ln_b[ly*DD + k];
      tile[k*136 + n] = f2b(gk*v);
      c1a += gk*v; c2a += bk*v;
    }
    c1p[tid] = c1a; c2p[tid] = c2a;
    __syncthreads();
    if (tid < DD) {
      ws[WS_C1 + ly*DD + tid] = c1p[tid] + c1p[tid+128];
      ws[WS_C2 + ly*DD + tid] = c2p[tid] + c2p[tid+128] + s4_inb[ly*DD + tid];
    }
    unsigned short* wgt = (unsigned short*)(ws + WS_WGT_F);
    for (int o = tid; o < DD*DD; o += 256) {
      int nn = o >> 7, k = o & 127;
      wgt[ly*DD*DD + o] = tile[k*136 + nn];
    }
    __syncthreads();
    for (int j = 0; j < 64; ++j) {
      int k = (tid >> 7) + 2*j;
      tile[k*136 + n] = f2b(s4_outW[((size_t)ly*DD + k)*DD + n]);
    }
    __syncthreads();
    unsigned short* wot = (unsigned short*)(ws + WS_WOT_F);
    for (int o = tid; o < DD*DD; o += 256) {
      int nn = o >> 7, k = o & 127;
      wot[ly*DD*DD + o] = tile[k*136 + nn];
    }
  } else if (blk < 27) {
    // ---- FIR taps for (ly,cx) -> KTAB ----
    __shared__ float part[256];
    int ly = (blk - 3) >> 3, cx = (blk - 3) & 7;
    int dt = tid & 31, nc = tid >> 5;
    const float* lre = lam_re + (ly*NCH + cx)*NST;
    const float* lim = lam_im + (ly*NCH + cx)*NST;
    const float* bn  = Bn  + (ly*NCH + cx)*NST;
    const float* cre = Cre + (ly*NCH + cx)*NST;
    const float* cim = Cim + (ly*NCH + cx)*NST;
    float td = (float)dt, acc = 0.f;
    for (int nn = nc*8; nn < nc*8 + 8; ++nn) {
      float e = expf(lre[nn]*td);
      float ang = lim[nn]*td;
      acc += bn[nn]*(cre[nn]*cosf(ang) - cim[nn]*sinf(ang))*e;
    }
    part[tid] = acc;
    __syncthreads();
    if (tid < 32) {
      float a = 0.f;
      #pragma unroll
      for (int i = 0; i < 8; ++i) a += part[i*32 + tid];
      ws[WS_KTAB + (ly*NCH + cx)*TAPS + tid] = a;
    }
  } else if (blk == 27) {
    // ---- BASE + GAW + ASCAL, all via LDS staging (no serial global chains) ----
    __shared__ float emb[BB*48];        // per-b: 32 singer + 16 lang
    __shared__ float w2[48*DD];         // inW rows 64..111
    __shared__ float r1[DD], r2[DD];
    for (int o = tid; o < 48*DD; o += 256) w2[o] = inW[64*DD + o];   // coalesced
    if (tid < BB*32) {                  // tid 0..255: singer emb
      int b = tid >> 5, j = tid & 31;
      emb[b*48 + j] = singer_emb[singer_id[b]*32 + j];
    }
    if (tid < BB*16) {                  // tid 0..127: lang emb (disjoint emb region)
      int b = tid >> 4, j = tid & 15;
      emb[b*48 + 32 + j] = lang_emb[language_id[b]*16 + j];
    }
    if (tid < DD) {
      float gw_ = attn_g[tid]*attn_w[tid];
      float bw  = attn_lnb[tid]*attn_w[tid];
      ws[WS_GAW + tid] = gw_;
      r1[tid] = gw_; r2[tid] = bw;
    }
    __syncthreads();
    for (int o = tid; o < BB*DD; o += 256) {
      int b = o >> 7, d = o & 127;
      float acc = inb[d];
      #pragma unroll
      for (int j = 0; j < 48; ++j) acc += emb[b*48 + j]*w2[j*DD + d];
      ws[WS_BASE + o] = acc;
    }
    if (tid == 0) {
      float c1s = 0.f, c2s = 0.f;
      for (int d = 0; d < DD; ++d) { c1s += r1[d]; c2s += r2[d]; }
      ws[WS_ASCAL+0] = c1s;
      ws[WS_ASCAL+1] = c2s + attn_bias[0];
    }
  } else {
    // ---- wo2t for head hd: [192n][64k] via LDS ----
    __shared__ float gw[64*200];
    int hd = blk - 28;
    for (int k = 0; k < 64; ++k) {
      if (tid < 192) gw[k*200 + tid] = genW_o[((size_t)hd*64 + k)*192 + tid];
    }
    __syncthreads();
    unsigned short* wo2t = (unsigned short*)(ws + WS_WO2T_F);
    for (int o = tid; o < 192*64; o += 256) {
      int nn = o >> 6, k = o & 63;
      wo2t[(size_t)hd*192*64 + o] = f2b(gw[k*200 + nn]);
    }
  }
}

// ================= K1p: embed + input proj + LN + SiLU -> h (fp32) + fused ly0 LN+in_proj -> z0 =====
__global__ __launch_bounds__(256) void k1p_input(
    const int* phone_seq, const float* f0, const float* phone_emb,
    const float* inW, const float* inln_g, const float* inln_b, float* ws)
{
  __shared__ __align__(16) float pm[64*72];
  __shared__ __align__(16) unsigned short hm[64*136];   // bf16 h tile for z0 MFMA
  __shared__ int   ps[64];
  __shared__ float fv[64];
  __shared__ float rs_s[64], mrs_s[64];
  int tid = threadIdx.x;
  size_t gbase = (size_t)blockIdx.x * 64;
  if (tid < 64) { ps[tid] = phone_seq[gbase + tid]; fv[tid] = f0[gbase + tid]; }
  __syncthreads();
  #pragma unroll
  for (int j = 0; j < 4; ++j) {
    int idx4 = tid + 256*j;
    int tok = idx4 >> 4, col = idx4 & 15;
    float4 v = *(const float4*)(phone_emb + (size_t)ps[tok]*64 + col*4);
    *(float4*)(pm + tok*72 + col*4) = v;
  }
  __syncthreads();
  int ti = tid >> 5, di = tid & 31, d0 = di*4;
  float acc[8][4];
  #pragma unroll
  for (int i = 0; i < 8; ++i) { acc[i][0]=0.f; acc[i][1]=0.f; acc[i][2]=0.f; acc[i][3]=0.f; }
  for (int kk = 0; kk < 64; kk += 4) {
    float4 w0 = *(const float4*)(inW + (kk+0)*DD + d0);
    float4 w1 = *(const float4*)(inW + (kk+1)*DD + d0);
    float4 w2 = *(const float4*)(inW + (kk+2)*DD + d0);
    float4 w3 = *(const float4*)(inW + (kk+3)*DD + d0);
    #pragma unroll
    for (int i = 0; i < 8; ++i) {
      float4 a = *(float4*)(pm + (ti*8 + i)*72 + kk);
      acc[i][0] += a.x*w0.x + a.y*w1.x + a.z*w2.x + a.w*w3.x;
      acc[i][1] += a.x*w0.y + a.y*w1.y + a.z*w2.y + a.w*w3.y;
      acc[i][2] += a.x*w0.z + a.y*w1.z + a.z*w2.z + a.w*w3.z;
      acc[i][3] += a.x*w0.w + a.y*w1.w + a.z*w2.w + a.w*w3.w;
    }
  }
  float4 w112 = *(const float4*)(inW + 112*DD + d0);
  int b = (int)(gbase >> 13);
  float4 bs  = *(const float4*)(ws + WS_BASE + b*DD + d0);
  float4 lg4 = *(const float4*)(inln_g + d0);
  float4 lb4 = *(const float4*)(inln_b + d0);
  float s2[8], ss2[8];
  #pragma unroll
  for (int i = 0; i < 8; ++i) {
    int tok = ti*8 + i;
    float fz = fv[tok];
    float y0 = acc[i][0] + fz*w112.x + bs.x;
    float y1 = acc[i][1] + fz*w112.y + bs.y;
    float y2 = acc[i][2] + fz*w112.z + bs.z;
    float y3 = acc[i][3] + fz*w112.w + bs.w;
    float s  = y0+y1+y2+y3;
    float ss = y0*y0+y1*y1+y2*y2+y3*y3;
    #pragma unroll
    for (int m = 16; m >= 1; m >>= 1) { s += __shfl_xor(s, m); ss += __shfl_xor(ss, m); }
    float mean = s * 0.0078125f;
    float var  = ss * 0.0078125f - mean*mean;
    float rstd = rsqrtf(var + 1e-5f);
    y0 = silu_f((y0 - mean)*rstd*lg4.x + lb4.x);
    y1 = silu_f((y1 - mean)*rstd*lg4.y + lb4.y);
    y2 = silu_f((y2 - mean)*rstd*lg4.z + lb4.z);
    y3 = silu_f((y3 - mean)*rstd*lg4.w + lb4.w);
    *(float4*)(ws + WS_H + (gbase + tok)*DD + d0) = make_float4(y0,y1,y2,y3);
    us4 p; p.x = f2b(y0); p.y = f2b(y1); p.z = f2b(y2); p.w = f2b(y3);
    *(us4*)(hm + tok*136 + d0) = p;
    s2[i]  = y0+y1+y2+y3;
    ss2[i] = y0*y0+y1*y1+y2*y2+y3*y3;
  }
  #pragma unroll
  for (int m = 16; m >= 1; m >>= 1) {
    #pragma unroll
    for (int i = 0; i < 8; ++i) { s2[i] += __shfl_xor(s2[i], m); ss2[i] += __shfl_xor(ss2[i], m); }
  }
  if (di == 0) {
    #pragma unroll
    for (int i = 0; i < 8; ++i) {
      int tok = ti*8 + i;
      float mean = s2[i]*0.0078125f;
      float var  = ss2[i]*0.0078125f - mean*mean;
      float rstd = rsqrtf(var + 1e-5f);
      rs_s[tok] = rstd; mrs_s[tok] = mean*rstd;
    }
  }
  __syncthreads();
  // ---- z0 = folded-LN(h0) @ Wg0 via MFMA ----
  int w = tid >> 6, lane = tid & 63, q = lane >> 4, c = lane & 15;
  int m16 = w*16;
  const unsigned short* wgt = (const unsigned short*)(ws + WS_WGT_F);  // ly 0
  bf16x8 aF[4];
  #pragma unroll
  for (int kk = 0; kk < 4; ++kk)
    aF[kk] = *(const bf16x8*)(hm + (m16 + c)*136 + kk*32 + q*8);
  float rsv[4], mrv[4];
  #pragma unroll
  for (int r = 0; r < 4; ++r) { int row = m16 + q*4 + r; rsv[r] = rs_s[row]; mrv[r] = mrs_s[row]; }
  unsigned short* zb = (unsigned short*)(ws + WS_ZB_F);
  #pragma unroll
  for (int nt = 0; nt < 8; ++nt) {
    f32x4 za = {0.f,0.f,0.f,0.f};
    #pragma unroll
    for (int kk = 0; kk < 4; ++kk) {
      bf16x8 bF = *(const bf16x8*)(wgt + (nt*16 + c)*DD + kk*32 + q*8);
      za = MFMA16(aF[kk], bF, za);
    }
    int col = nt*16 + c;
    float c1v = ws[WS_C1 + col];
    float c2v = ws[WS_C2 + col];
    #pragma unroll
    for (int r = 0; r < 4; ++r) {
      float zv = rsv[r]*za[r] - mrv[r]*c1v + c2v;
      zb[(gbase + m16 + q*4 + r)*DD + col] = f2b(zv);
    }
  }
}

// ===== K3p: FIR conv + skip + MFMA out_proj + SiLU + residual (+logits) + fused next-layer LN+in_proj
__global__ __launch_bounds__(256) void k3p_conv_out(
    float* ws, const float* s4_outb, const float* Dc, int ly, int do_logits, int do_z)
{
  __shared__ __align__(16) unsigned short zw[128*128];  // conv window; reused as hn bf16 tile after conv
  __shared__ __align__(16) unsigned short ym[64*136];   // bf16 A-tile for out_proj
  __shared__ float k2t[8*64];
  __shared__ float dcs[8];
  __shared__ float rs2[64], mrs2[64];
  int tid = threadIdx.x, blk = blockIdx.x;
  int b  = blk >> 7;
  int t0 = (blk & 127) * 64;
  const unsigned short* zbp = (const unsigned short*)(ws + WS_ZB_F);
  #pragma unroll
  for (int j = 0; j < 8; ++j) {
    int idx8 = tid + 256*j;            // 128 tok x 16 ushort8
    int tok = idx8 >> 4, c8 = idx8 & 15;
    int t = t0 - 32 + tok;
    bf16x8 v = {0,0,0,0,0,0,0,0};
    if (t >= 0 && t < LL) v = *(const bf16x8*)(zbp + ((size_t)b*LL + t)*DD + c8*8);
    *(bf16x8*)(zw + tok*DD + c8*8) = v;
  }
  for (int o = tid; o < 512; o += 256) {     // K2[j]: j=-31..32 -> m=0..63
    int c = o >> 6, m = o & 63;
    int idx = (m <= 31) ? (31 - m) : (m - 32);
    k2t[o] = ws[WS_KTAB + (ly*NCH + c)*TAPS + idx];
  }
  if (tid < 8) dcs[tid] = Dc[ly*NCH + tid];
  __syncthreads();
  // conv: 2 passes, thread = (token half16, channel)
  #pragma unroll
  for (int p = 0; p < 2; ++p) {
    int half = p*2 + (tid >> 7), ch = tid & 127, cx = ch >> 4;
    int base = 1 + half*16;
    float ring[16], accv[16];
    #pragma unroll
    for (int x = 0; x < 16; ++x) { ring[x] = b2f(zw[(base + x)*DD + ch]); accv[x] = 0.f; }
    #pragma unroll
    for (int m = 0; m < 64; ++m) {
      float kf = k2t[cx*64 + m];
      #pragma unroll
      for (int i = 0; i < 16; ++i) accv[i] += kf * ring[(m + i) & 15];
      if (m < 63) ring[m & 15] = b2f(zw[(base + m + 16)*DD + ch]);
    }
    float dcv = dcs[cx];
    #pragma unroll
    for (int i = 0; i < 16; ++i) {
      int tl = half*16 + i;
      ym[tl*136 + ch] = f2b(accv[i] + dcv * b2f(zw[(32 + tl)*DD + ch]));
    }
  }
  __syncthreads();
  // MFMA out_proj: wave w -> rows w*16..+15. After this sync zw is dead -> reuse as hn bf16 tile.
  unsigned short* hm2 = zw;   // [64][136] bf16 hn tile
  int w = tid >> 6, lane = tid & 63, q = lane >> 4, c = lane & 15;
  int m16 = w*16;
  const unsigned short* wot = (const unsigned short*)(ws + WS_WOT_F) + ly*DD*DD;
  bf16x8 aF[4];
  #pragma unroll
  for (int kk = 0; kk < 4; ++kk)
    aF[kk] = *(const bf16x8*)(ym + (m16 + c)*136 + kk*32 + q*8);
  float* hbuf = ws + WS_H;
  float c1s = ws[WS_ASCAL+0], c2s = ws[WS_ASCAL+1];
  float sr[4] = {0,0,0,0}, ssr[4] = {0,0,0,0}, dtr[4] = {0,0,0,0};
  #pragma unroll
  for (int nt = 0; nt < 8; ++nt) {
    f32x4 acc = {0.f,0.f,0.f,0.f};
    #pragma unroll
    for (int kk = 0; kk < 4; ++kk) {
      bf16x8 bF = *(const bf16x8*)(wot + (nt*16 + c)*DD + kk*32 + q*8);
      acc = MFMA16(aF[kk], bF, acc);
    }
    int col = nt*16 + c;
    float ob = s4_outb[ly*DD + col];
    float gw = ws[WS_GAW + col];
    #pragma unroll
    for (int r = 0; r < 4; ++r) {
      size_t gofs = ((size_t)b*LL + t0 + m16 + q*4 + r)*DD + col;
      float hold = hbuf[gofs];
      float hn = hold + silu_f(acc[r] + ob);
      hbuf[gofs] = hn;
      hm2[(m16 + q*4 + r)*136 + col] = f2b(hn);
      sr[r] += hn; ssr[r] += hn*hn;
      if (do_logits) dtr[r] += hn*gw;
    }
  }
  #pragma unroll
  for (int m = 8; m >= 1; m >>= 1) {
    #pragma unroll
    for (int r = 0; r < 4; ++r) {
      sr[r]  += __shfl_xor(sr[r],  m);
      ssr[r] += __shfl_xor(ssr[r], m);
      if (do_logits) dtr[r] += __shfl_xor(dtr[r], m);
    }
  }
  if (c < 4) {
    int r = c;
    float mean = sr[r]*0.0078125f;
    float var  = ssr[r]*0.0078125f - mean*mean;
    float rstd = rsqrtf(var + 1e-5f);
    int row = m16 + q*4 + r;
    if (do_z) { rs2[row] = rstd; mrs2[row] = mean*rstd; }
    if (do_logits)
      ws[WS_LOGITS + (size_t)b*LL + t0 + row] = rstd*dtr[r] - mean*rstd*c1s + c2s;
  }
  if (do_z) {
    __syncthreads();
    const unsigned short* wgt2 = (const unsigned short*)(ws + WS_WGT_F) + (ly+1)*DD*DD;
    bf16x8 aF2[4];
    #pragma unroll
    for (int kk = 0; kk < 4; ++kk)
      aF2[kk] = *(const bf16x8*)(hm2 + (m16 + c)*136 + kk*32 + q*8);
    float rsv[4], mrv[4];
    #pragma unroll
    for (int r = 0; r < 4; ++r) { int row = m16 + q*4 + r; rsv[r] = rs2[row]; mrv[r] = mrs2[row]; }
    unsigned short* zb = (unsigned short*)(ws + WS_ZB_F);
    size_t gbase = (size_t)b*LL + t0;
    #pragma unroll
    for (int nt = 0; nt < 8; ++nt) {
      f32x4 za = {0.f,0.f,0.f,0.f};
      #pragma unroll
      for (int kk = 0; kk < 4; ++kk) {
        bf16x8 bF = *(const bf16x8*)(wgt2 + (nt*16 + c)*DD + kk*32 + q*8);
        za = MFMA16(aF2[kk], bF, za);
      }
      int col = nt*16 + c;
      float c1v = ws[WS_C1 + (ly+1)*DD + col];
      float c2v = ws[WS_C2 + (ly+1)*DD + col];
      #pragma unroll
      for (int r = 0; r < 4; ++r) {
        float zv = rsv[r]*za[r] - mrv[r]*c1v + c2v;
        zb[(gbase + m16 + q*4 + r)*DD + col] = f2b(zv);
      }
    }
  }
}

// ================= K5b: segmented softmax + weighted pool partials (NSEG=64 x 128 tokens) =====
__global__ __launch_bounds__(256) void k5b_pool(float* ws)
{
  int blk = blockIdx.x, tid = threadIdx.x;
  int b = blk >> 6, seg = blk & 63;
  const float* lg = ws + WS_LOGITS + (size_t)b*LL + seg*128;
  __shared__ float ev[128];
  __shared__ float red[4], red2[4];
  __shared__ float vr[2][128];
  float a0 = (tid < 128) ? lg[tid] : -1e30f;
  float mx = a0;
  #pragma unroll
  for (int m = 32; m >= 1; m >>= 1) mx = fmaxf(mx, __shfl_xor(mx, m));
  if ((tid & 63) == 0) red[tid >> 6] = mx;
  __syncthreads();
  float M = fmaxf(fmaxf(red[0], red[1]), fmaxf(red[2], red[3]));
  float e0 = (tid < 128) ? expf(a0 - M) : 0.f;
  if (tid < 128) ev[tid] = e0;
  float s = e0;
  #pragma unroll
  for (int m = 32; m >= 1; m >>= 1) s += __shfl_xor(s, m);
  if ((tid & 63) == 0) red2[tid >> 6] = s;
  __syncthreads();
  float S = red2[0] + red2[1] + red2[2] + red2[3];
  int ls = tid >> 7, d = tid & 127;
  const float* hb = ws + WS_H + ((size_t)b*LL + seg*128)*DD;
  float acc = 0.f;
  for (int jj = 0; jj < 64; ++jj) {
    int tok = jj*2 + ls;
    acc += ev[tok] * hb[(size_t)tok*DD + d];
  }
  vr[ls][d] = acc;
  __syncthreads();
  if (tid < 128) ws[WS_SEGV + (size_t)(b*NSEG + seg)*DD + tid] = vr[0][tid] + vr[1][tid];
  if (tid == 0) { ws[WS_SEGM + b*NSEG + seg] = M; ws[WS_SEGS + b*NSEG + seg] = S; }
}

// ================= K5c: combine pool + g (grid 8, per batch; all compute from LDS) =========
__global__ __launch_bounds__(256) void k5c_cond(
    float* ws, const float* gpW, const float* gpb)
{
  __shared__ float segv[NSEG*DD];   // 32 KB
  __shared__ float gpwl[DD*32];     // 16 KB
  __shared__ float wsg[NSEG];
  __shared__ float Ssh;
  __shared__ float gpre[DD];
  __shared__ float vr[2][DD];
  __shared__ float red[256];
  int b = blockIdx.x, tid = threadIdx.x;
  // coalesced stages (independent loads, MLP-pipelined)
  #pragma unroll
  for (int j = 0; j < 8; ++j) {
    int i4 = tid + 256*j;
    *(float4*)(segv + i4*4) = *(const float4*)(ws + WS_SEGV + (size_t)b*NSEG*DD + i4*4);
  }
  #pragma unroll
  for (int j = 0; j < 4; ++j) {
    int i4 = tid + 256*j;
    *(float4*)(gpwl + i4*4) = *(const float4*)(gpW + i4*4);
  }
  // segment stats: wave 0, one lane per segment, shfl tree
  if (tid < 64) {
    float m = ws[WS_SEGM + b*NSEG + tid];
    float s = ws[WS_SEGS + b*NSEG + tid];
    float M = m;
    #pragma unroll
    for (int x = 32; x >= 1; x >>= 1) M = fmaxf(M, __shfl_xor(M, x));
    float e = expf(m - M);
    float Sp = s*e;
    #pragma unroll
    for (int x = 32; x >= 1; x >>= 1) Sp += __shfl_xor(Sp, x);
    wsg[tid] = e;
    if (tid == 0) Ssh = Sp;
  }
  __syncthreads();
  {
    int ls = tid >> 7, d = tid & 127;
    float V = 0.f;
    #pragma unroll
    for (int sg = ls*32; sg < ls*32 + 32; ++sg)
      V += segv[sg*DD + d]*wsg[sg];
    vr[ls][d] = V;
  }
  __syncthreads();
  if (tid < DD) gpre[tid] = (vr[0][tid] + vr[1][tid]) / Ssh;
  __syncthreads();
  {
    int c = tid & 31, kc = tid >> 5;   // 8 chunks x 16 k
    float p = 0.f;
    for (int k = kc*16; k < kc*16 + 16; ++k) p += gpre[k]*gpwl[k*32 + c];
    red[tid] = p;
  }
  __syncthreads();
  if (tid < 32) {
    float a = gpb[tid];
    #pragma unroll
    for (int i = 0; i < 8; ++i) a += red[i*32 + tid];
    ws[WS_SCALE + b*32 + tid] = a;    // gg[b][32]
  }
}

// ========= K5d: FiLM (from LDS) + folded generator weights Wcat (bf16) + bias1 (grid 7) =====
__global__ __launch_bounds__(256) void k5d_fold(
    float* ws, const float* genW_h, const float* genb_h,
    const float* genW_s, const float* genb_s, const float* genW_sh, const float* genb_sh)
{
  __shared__ float wh[128*65];     // genW_h staged [k][j] (33.3 KB)
  __shared__ float gsw[32*DD];     // genW_s[hd] (16 KB)
  __shared__ float ghw[32*DD];     // genW_sh[hd] (16 KB)
  __shared__ float ggs[BB*32];     // gg (1 KB)
  __shared__ float scs[BB*DD];     // scale (4 KB)
  __shared__ float shs[BB*DD];     // shift (4 KB)
  __shared__ float red[256];
  int hd = blockIdx.x, tid = threadIdx.x;
  for (int o = tid; o < DD*64; o += 256) {
    int k = o >> 6, j = o & 63;
    wh[k*65 + j] = genW_h[(size_t)hd*DD*64 + o];   // coalesced
  }
  #pragma unroll
  for (int j = 0; j < 4; ++j) {
    int i4 = tid + 256*j;
    *(float4*)(gsw + i4*4) = *(const float4*)(genW_s  + (size_t)hd*32*DD + i4*4);
    *(float4*)(ghw + i4*4) = *(const float4*)(genW_sh + (size_t)hd*32*DD + i4*4);
  }
  ggs[tid] = ws[WS_SCALE + tid];     // 256 = BB*32, coalesced
  __syncthreads();
  // FiLM scale/shift for all (b,d), all-LDS inner loop
  for (int o = tid; o < BB*DD; o += 256) {
    int b = o >> 7, d = o & 127;
    float sc = genb_s[hd*DD + d], sh = genb_sh[hd*DD + d];
    #pragma unroll
    for (int c = 0; c < 32; ++c) {
      float g = ggs[b*32 + c];
      sc += g*gsw[c*DD + d];
      sh += g*ghw[c*DD + d];
    }
    scs[o] = sc; shs[o] = sh;
  }
  __syncthreads();
  unsigned short* wct = (unsigned short*)(ws + WS_WCT_F);
  for (int b = 0; b < BB; ++b) {
    for (int o = tid; o < 64*DD; o += 256) {
      int j = o >> 7, k = o & 127;
      wct[((size_t)b*448 + hd*64 + j)*DD + k] = f2b(scs[b*DD + k]*wh[k*65 + j]);
    }
    {
      int j = tid >> 2, kc = tid & 3;   // 64 j x 4 chunks of 32 k
      float p = 0.f;
      for (int k = kc*32; k < kc*32 + 32; ++k) p += shs[b*DD + k]*wh[k*65 + j];
      red[tid] = p;
      __syncthreads();
      if (tid < 64)
        ws[WS_BIAS1 + b*448 + hd*64 + tid] =
          genb_h[hd*64 + tid] + red[tid*4] + red[tid*4+1] + red[tid*4+2] + red[tid*4+3];
      __syncthreads();
    }
  }
}

// ================= K6: generator heads, M=64 tiles, 512 threads; launched as 2 half-grids =====
__global__ __launch_bounds__(512) void k6_heads(float* ws, const float* genb_o, float* out, int blk0)
{
  __shared__ __align__(16) unsigned short hm[64*136];   // bf16 h tile
  __shared__ __align__(16) unsigned short rm[64*456];   // bf16 r tile (448 + pad)
  int tid = threadIdx.x, blk = blockIdx.x + blk0;
  int b = blk >> 7, t0 = (blk & 127)*64;
  const float* hb = ws + WS_H + ((size_t)b*LL + t0)*DD;
  #pragma unroll
  for (int j = 0; j < 4; ++j) {
    int idx4 = tid + 512*j;                 // 64 tok x 32 float4
    int tok = idx4 >> 5, c4 = idx4 & 31;
    float4 v = *(const float4*)(hb + (size_t)idx4*4);
    us4 p; p.x = f2b(v.x); p.y = f2b(v.y); p.z = f2b(v.z); p.w = f2b(v.w);
    *(us4*)(hm + tok*136 + c4*4) = p;
  }
  __syncthreads();
  int w = tid >> 6, lane = tid & 63, q = lane >> 4, c = lane & 15;
  int mi = w & 3, nh = w >> 2;
  int m16 = mi*16;
  {
    bf16x8 aF[4];
    #pragma unroll
    for (int kk = 0; kk < 4; ++kk)
      aF[kk] = *(const bf16x8*)(hm + (m16 + c)*136 + kk*32 + q*8);
    const unsigned short* wct = (const unsigned short*)(ws + WS_WCT_F) + (size_t)b*448*DD;
    #pragma unroll 2
    for (int ntl = 0; ntl < 14; ++ntl) {
      int nt = nh*14 + ntl;
      f32x4 acc = {0.f,0.f,0.f,0.f};
      #pragma unroll
      for (int kk = 0; kk < 4; ++kk) {
        bf16x8 bF = *(const bf16x8*)(wct + ((size_t)nt*16 + c)*DD + kk*32 + q*8);
        acc = MFMA16(aF[kk], bF, acc);
      }
      int col = nt*16 + c;
      float bias = ws[WS_BIAS1 + b*448 + col];
      #pragma unroll
      for (int r = 0; r < 4; ++r)
        rm[(m16 + q*4 + r)*456 + col] = f2b(silu_f(acc[r] + bias));
    }
  }
  __syncthreads();
  {
    const unsigned short* wo2t = (const unsigned short*)(ws + WS_WO2T_F);
    int i0 = (nh == 0) ? 0 : 14;
    int i1 = (nh == 0) ? 14 : 27;
    #pragma unroll 2
    for (int i = i0; i < i1; ++i) {
      int hd = t_hd[i], nl = t_nl[i];
      bf16x8 aF0 = *(const bf16x8*)(rm + (m16 + c)*456 + hd*64 + q*8);
      bf16x8 aF1 = *(const bf16x8*)(rm + (m16 + c)*456 + hd*64 + 32 + q*8);
      f32x4 acc = {0.f,0.f,0.f,0.f};
      bf16x8 bF0 = *(const bf16x8*)(wo2t + ((size_t)hd*192 + nl*16 + c)*64 + q*8);
      bf16x8 bF1 = *(const bf16x8*)(wo2t + ((size_t)hd*192 + nl*16 + c)*64 + 32 + q*8);
      acc = MFMA16(aF0, bF0, acc);
      acc = MFMA16(aF1, bF1, acc);
      int cl = nl*16 + c;
      int di = c_dims_d[hd];
      if (cl < di) {
        float bo = genb_o[hd*192 + cl];
        #pragma unroll
        for (int r = 0; r < 4; ++r)
          out[((size_t)b*LL + t0 + m16 + q*4 + r)*NOUTD + c_offs_d[hd] + cl] = acc[r] + bo;
      }
    }
  }
}

// ================= launch =================
extern "C" void kernel_launch(void* const* d_in, const int* in_sizes, int n_in,
                              void* d_out, int out_size, void* d_ws, size_t ws_size,
                              hipStream_t stream) {
  const int*   phone_seq   = (const int*)  d_in[0];
  const int*   singer_id   = (const int*)  d_in[1];
  const int*   language_id = (const int*)  d_in[2];
  const float* f0          = (const float*)d_in[3];
  const float* phone_emb   = (const float*)d_in[4];
  const float* singer_emb  = (const float*)d_in[5];
  const float* lang_emb    = (const float*)d_in[6];
  const float* inW         = (const float*)d_in[7];
  const float* inb         = (const float*)d_in[8];
  const float* inln_g      = (const float*)d_in[9];
  const float* inln_b      = (const float*)d_in[10];
  const float* s4_ln_g     = (const float*)d_in[11];
  const float* s4_ln_b     = (const float*)d_in[12];
  const float* s4_inW      = (const float*)d_in[13];
  const float* s4_inb      = (const float*)d_in[14];
  const float* s4_outW     = (const float*)d_in[15];
  const float* s4_outb     = (const float*)d_in[16];
  const float* lam_re      = (const float*)d_in[17];
  const float* lam_im      = (const float*)d_in[18];
  const float* Bn          = (const float*)d_in[19];
  const float* C_re        = (const float*)d_in[20];
  const float* C_im        = (const float*)d_in[21];
  const float* Dc          = (const float*)d_in[22];
  const float* attn_g      = (const float*)d_in[23];
  const float* attn_lnb    = (const float*)d_in[24];
  const float* attn_w      = (const float*)d_in[25];
  const float* attn_bias   = (const float*)d_in[26];
  const float* gpW         = (const float*)d_in[27];
  const float* gpb         = (const float*)d_in[28];
  const float* genW_s      = (const float*)d_in[29];
  const float* genb_s      = (const float*)d_in[30];
  const float* genW_sh     = (const float*)d_in[31];
  const float* genb_sh     = (const float*)d_in[32];
  const float* genW_h      = (const float*)d_in[33];
  const float* genb_h      = (const float*)d_in[34];
  const float* genW_o      = (const float*)d_in[35];
  const float* genb_o      = (const float*)d_in[36];
  float* ws  = (float*)d_ws;
  float* out = (float*)d_out;

  k0_setup<<<35, 256, 0, stream>>>(s4_ln_g, s4_ln_b, s4_inW, s4_inb, s4_outW,
                                   lam_re, lam_im, Bn, C_re, C_im,
                                   attn_g, attn_lnb, attn_w, attn_bias,
                                   singer_id, language_id, singer_emb, lang_emb, inW, inb,
                                   genW_o, ws);
  k1p_input<<<BB*LL/64, 256, 0, stream>>>(phone_seq, f0, phone_emb, inW, inln_g, inln_b, ws);
  for (int ly = 0; ly < 3; ++ly) {
    k3p_conv_out<<<BB*LL/64, 256, 0, stream>>>(ws, s4_outb, Dc, ly,
                                               (ly == 2) ? 1 : 0, (ly < 2) ? 1 : 0);
  }
  k5b_pool<<<BB*NSEG, 256, 0, stream>>>(ws);
  k5c_cond<<<BB, 256, 0, stream>>>(ws, gpW, gpb);
  k5d_fold<<<7, 256, 0, stream>>>(ws, genW_h, genb_h, genW_s, genb_s, genW_sh, genb_sh);
  k6_heads<<<512, 512, 0, stream>>>(ws, genb_o, out, 0);
  k6_heads<<<512, 512, 0, stream>>>(ws, genb_o, out, 512);
}